// Round 9
// baseline (640.922 us; speedup 1.0000x reference)
//
#include <hip/hip_runtime.h>

#define T_TOK 8192
#define H_DIM 1024
#define I_DIM 3584
#define NEXP 8
#define MAX_T256 72            // sum ceil(cnt_e/256) <= 64 + 7, padded
#define NT16 (H_DIM / 64)      // 16 K-tiles for gemm1
#define NT2 (I_DIM / 64)       // 56 K-tiles for gemm2

typedef __attribute__((ext_vector_type(4))) float f32x4;
typedef __attribute__((ext_vector_type(8))) short bf16x8;

__device__ __forceinline__ unsigned short f2bf(float f) {
    union { float f; unsigned u; } v; v.f = f;
    unsigned r = v.u + 0x7FFFu + ((v.u >> 16) & 1u);
    return (unsigned short)(r >> 16);
}

__device__ __forceinline__ void gload16(const unsigned short* g, unsigned short* l) {
    __builtin_amdgcn_global_load_lds(
        (const __attribute__((address_space(1))) void*)g,
        (__attribute__((address_space(3))) void*)l, 16, 0, 0);
}

#define SBAR asm volatile("s_barrier" ::: "memory")
#define VMW8 asm volatile("s_waitcnt vmcnt(8)" ::: "memory")

// ================= fast path =================

// router: logits -> softmax -> top2; emits pair[t], combine[t][8], and xb (bf16 x)
__global__ void router_kernel(const float* __restrict__ x, const float* __restrict__ gw,
                              const float* __restrict__ gb, unsigned short* __restrict__ xb,
                              float* __restrict__ combine, int* __restrict__ pair) {
    int wave = threadIdx.x >> 6, lane = threadIdx.x & 63;
    int t = blockIdx.x * 4 + wave;
    float acc[NEXP];
#pragma unroll
    for (int e = 0; e < NEXP; ++e) acc[e] = 0.f;
    const float4* xr = (const float4*)(x + (size_t)t * H_DIM);
#pragma unroll
    for (int j = 0; j < 4; ++j) {
        int c = j * 64 + lane;
        float4 xv = xr[c];
        ushort4 o = { f2bf(xv.x), f2bf(xv.y), f2bf(xv.z), f2bf(xv.w) };
        *(ushort4*)(xb + (size_t)t * H_DIM + c * 4) = o;
#pragma unroll
        for (int e = 0; e < NEXP; ++e) {
            float4 gv = ((const float4*)(gw + (size_t)e * H_DIM))[c];
            acc[e] += xv.x * gv.x + xv.y * gv.y + xv.z * gv.z + xv.w * gv.w;
        }
    }
#pragma unroll
    for (int off = 32; off; off >>= 1)
#pragma unroll
        for (int e = 0; e < NEXP; ++e) acc[e] += __shfl_xor(acc[e], off, 64);
    if (lane == 0) {
        float logit[NEXP], mx = -1e30f;
#pragma unroll
        for (int e = 0; e < NEXP; ++e) { logit[e] = acc[e] + gb[e]; mx = fmaxf(mx, logit[e]); }
        float p[NEXP], s = 0.f;
#pragma unroll
        for (int e = 0; e < NEXP; ++e) { p[e] = expf(logit[e] - mx); s += p[e]; }
        float inv = 1.f / s;
#pragma unroll
        for (int e = 0; e < NEXP; ++e) p[e] *= inv;
        int i1 = 0;
#pragma unroll
        for (int e = 1; e < NEXP; ++e) if (p[e] > p[i1]) i1 = e;
        int i2 = -1;
#pragma unroll
        for (int e = 0; e < NEXP; ++e) if (e != i1 && (i2 < 0 || p[e] > p[i2])) i2 = e;
        float4 c0, c1;
        c0.x = (0 == i1 || 0 == i2) ? p[0] : 0.f;  c0.y = (1 == i1 || 1 == i2) ? p[1] : 0.f;
        c0.z = (2 == i1 || 2 == i2) ? p[2] : 0.f;  c0.w = (3 == i1 || 3 == i2) ? p[3] : 0.f;
        c1.x = (4 == i1 || 4 == i2) ? p[4] : 0.f;  c1.y = (5 == i1 || 5 == i2) ? p[5] : 0.f;
        c1.z = (6 == i1 || 6 == i2) ? p[6] : 0.f;  c1.w = (7 == i1 || 7 == i2) ? p[7] : 0.f;
        *(float4*)(combine + (size_t)t * NEXP) = c0;
        *(float4*)(combine + (size_t)t * NEXP + 4) = c1;
        pair[t] = i1 | (i2 << 8);
    }
}

// deterministic, atomic-free list builder; 256-row tile granularity
__global__ void build_lists_kernel(const int* __restrict__ pair, int* __restrict__ frows,
                                   int* __restrict__ tile_e, int* __restrict__ tile_valid,
                                   int* __restrict__ ntiles) {
    const int e = blockIdx.x;
    const int tid = threadIdx.x;
    const int wave = tid >> 6, lane = tid & 63;
    __shared__ int wtot[16][NEXP];
    __shared__ int stot[NEXP];
    __shared__ int wcnt[16];

    int myp[8];
    int tcnt[NEXP] = {0, 0, 0, 0, 0, 0, 0, 0};
#pragma unroll
    for (int c = 0; c < 8; ++c) {
        int pr = pair[c * 1024 + tid];
        myp[c] = pr;
        int e1 = pr & 255, e2 = (pr >> 8) & 255;
#pragma unroll
        for (int j = 0; j < NEXP; ++j) {
            unsigned long long m = __ballot(e1 == j || e2 == j);
            if (lane == 0) tcnt[j] += (int)__popcll(m);
        }
    }
    if (lane == 0) {
#pragma unroll
        for (int j = 0; j < NEXP; ++j) wtot[wave][j] = tcnt[j];
    }
    __syncthreads();
    if (tid < NEXP) {
        int s = 0;
        for (int w = 0; w < 16; ++w) s += wtot[w][tid];
        stot[tid] = s;
    }
    __syncthreads();

    int gbase = 0, tbase = 0, totTiles = 0;
#pragma unroll
    for (int j = 0; j < NEXP; ++j) {
        int tj = (stot[j] + 255) >> 8;
        if (j < e) { gbase += tj << 8; tbase += tj; }
        totTiles += tj;
    }
    const int cnt = stot[e];
    const int mytiles = (cnt + 255) >> 8;

    int base = gbase;
    for (int c = 0; c < 8; ++c) {
        int pr = myp[c];
        bool pred = ((pr & 255) == e) || (((pr >> 8) & 255) == e);
        unsigned long long m = __ballot(pred);
        if (lane == 0) wcnt[wave] = (int)__popcll(m);
        __syncthreads();
        int wb = 0;
        for (int w = 0; w < wave; ++w) wb += wcnt[w];
        int ctot = 0;
        for (int w = 0; w < 16; ++w) ctot += wcnt[w];
        if (pred) {
            int wp = (int)__popcll(m & ((1ull << lane) - 1ull));
            frows[base + wb + wp] = c * 1024 + tid;
        }
        base += ctot;
        __syncthreads();
    }
    if (cnt > 0) {
        int first = frows[gbase];
        for (int p = cnt + tid; p < (mytiles << 8); p += 1024) frows[gbase + p] = first;
        if (tid < mytiles) {
            tile_e[tbase + tid] = e;
            int v = cnt - (tid << 8);
            tile_valid[tbase + tid] = v > 256 ? 256 : v;
        }
    }
    if (e == 0 && tid == 0) ntiles[0] = totTiles;
}

// weights f32 -> bf16 (grid-stride, 8 elems/thread)
__global__ void wcvt_kernel(const float* __restrict__ src, unsigned short* __restrict__ dst, int n8) {
    int stride = gridDim.x * blockDim.x;
    for (int i = blockIdx.x * blockDim.x + threadIdx.x; i < n8; i += stride) {
        const float4* p = (const float4*)src + (size_t)i * 2;
        float4 a = p[0], b = p[1];
        uint4 o;
        o.x = (unsigned)f2bf(a.x) | ((unsigned)f2bf(a.y) << 16);
        o.y = (unsigned)f2bf(a.z) | ((unsigned)f2bf(a.w) << 16);
        o.z = (unsigned)f2bf(b.x) | ((unsigned)f2bf(b.y) << 16);
        o.w = (unsigned)f2bf(b.z) | ((unsigned)f2bf(b.w) << 16);
        *(uint4*)(dst + (size_t)i * 8) = o;
    }
}

// w1,w3 f32 -> interleaved bf16 w13i[e][7168][1024]:
// row r: s=r&31, rg=r>>5; s<16 -> w1 row rg*16+s ; s>=16 -> w3 row rg*16+s-16
__global__ void wcvt13_kernel(const float* __restrict__ w1, const float* __restrict__ w3,
                              unsigned short* __restrict__ dst, int n8) {
    int stride = gridDim.x * blockDim.x;
    for (int g = blockIdx.x * blockDim.x + threadIdx.x; g < n8; g += stride) {
        int col = (g & 127) * 8;
        int er = g >> 7;
        int r = er % 7168;
        int e = er / 7168;
        int s = r & 31, rg = r >> 5;
        const float* src = (s < 16)
            ? (w1 + ((size_t)e * I_DIM + rg * 16 + s) * H_DIM + col)
            : (w3 + ((size_t)e * I_DIM + rg * 16 + (s - 16)) * H_DIM + col);
        float4 a = *(const float4*)src;
        float4 b = *(const float4*)(src + 4);
        uint4 o;
        o.x = (unsigned)f2bf(a.x) | ((unsigned)f2bf(a.y) << 16);
        o.y = (unsigned)f2bf(a.z) | ((unsigned)f2bf(a.w) << 16);
        o.z = (unsigned)f2bf(b.x) | ((unsigned)f2bf(b.y) << 16);
        o.w = (unsigned)f2bf(b.z) | ((unsigned)f2bf(b.w) << 16);
        *(uint4*)(dst + (size_t)g * 8) = o;
    }
}

// shared MFMA cluster macro (16 MFMAs, setprio-wrapped)
#define MM_Q(AF, BF, MB) do { \
    __builtin_amdgcn_s_setprio(1); \
    _Pragma("unroll") for (int i_ = 0; i_ < 4; ++i_) \
    { _Pragma("unroll") for (int n_ = 0; n_ < 4; ++n_) \
        acc[MB + i_][n_] = __builtin_amdgcn_mfma_f32_16x16x32_bf16(AF[i_], BF[n_], acc[MB + i_][n_], 0, 0, 0); } \
    __builtin_amdgcn_s_setprio(0); } while (0)

// ---------------- GEMM1: 256x256 tile, 8 waves, counted-vmcnt pipeline, 2 barriers/K-tile ----------------
// (R8-verified structure; see R8 comments for hazard analysis and vmcnt(8) invariant.)
__global__ __launch_bounds__(512, 2)
void gemm1_256_kernel(const unsigned short* __restrict__ xb,
                      const unsigned short* __restrict__ w13b,
                      unsigned short* __restrict__ h_bf,
                      const int* __restrict__ frows, const int* __restrict__ tile_e,
                      const int* __restrict__ ntiles) {
    const int bt = blockIdx.y;
    if (bt >= ntiles[0]) return;
    __shared__ unsigned short lds[65536];   // A at 0, B at elem 32768; halves of 8192 elems
    const int e = tile_e[bt];
    const int n0 = blockIdx.x * 256;
    const int tid = threadIdx.x;
    const int w = tid >> 6, lane = tid & 63;
    const int wm = w >> 2, wn = w & 3;

    const int srow = tid >> 2;
    const int swcol = 8 * ((tid & 3) ^ ((srow >> 1) & 3));
    const unsigned short* aSrc[2];
    const unsigned short* bSrc[2];
    aSrc[0] = xb + (size_t)frows[bt * 256 + srow] * H_DIM + swcol;
    aSrc[1] = xb + (size_t)frows[bt * 256 + srow + 128] * H_DIM + swcol;
    bSrc[0] = w13b + ((size_t)e * 7168 + n0 + srow) * H_DIM + swcol;
    bSrc[1] = w13b + ((size_t)e * 7168 + n0 + srow + 128) * H_DIM + swcol;
    unsigned short* aDst = &lds[w * 512];
    unsigned short* bDst = &lds[32768 + w * 512];

    f32x4 acc[8][4] = {};

#define STAGE_A(DT, ST, KH) do { int kofs_ = (ST) * 64 + (KH) * 32; \
    unsigned short* d_ = aDst + (((DT) & 1) * 2 + (KH)) * 8192; \
    gload16(aSrc[0] + kofs_, d_); gload16(aSrc[1] + kofs_, d_ + 4096); } while (0)
#define STAGE_B(DT, ST, KH) do { int kofs_ = (ST) * 64 + (KH) * 32; \
    unsigned short* d_ = bDst + (((DT) & 1) * 2 + (KH)) * 8192; \
    gload16(bSrc[0] + kofs_, d_); gload16(bSrc[1] + kofs_, d_ + 4096); } while (0)
#define LDA(AF, D, KH, MH) do { \
    _Pragma("unroll") for (int i_ = 0; i_ < 4; ++i_) { \
        int row_ = wm * 128 + ((MH) * 4 + i_) * 16 + (lane & 15); \
        AF[i_] = *(const bf16x8*)&lds[((D) * 2 + (KH)) * 8192 + row_ * 32 + 8 * ((lane >> 4) ^ ((row_ >> 1) & 3))]; } } while (0)
#define LDB(BF, D, KH) do { \
    _Pragma("unroll") for (int i_ = 0; i_ < 4; ++i_) { \
        int row_ = wn * 64 + i_ * 16 + (lane & 15); \
        BF[i_] = *(const bf16x8*)&lds[32768 + ((D) * 2 + (KH)) * 8192 + row_ * 32 + 8 * ((lane >> 4) ^ ((row_ >> 1) & 3))]; } } while (0)

    STAGE_A(0, 0, 0); STAGE_B(0, 0, 0);
    STAGE_A(0, 0, 1); STAGE_B(0, 0, 1);
    STAGE_A(1, 1 < NT16 ? 1 : NT16 - 1, 0); STAGE_B(1, 1 < NT16 ? 1 : NT16 - 1, 0);
    VMW8; SBAR;

    for (int kt = 0; kt < NT16; ++kt) {
        const int d = kt & 1;
        const int s1 = (kt + 1 < NT16) ? kt + 1 : NT16 - 1;
        const int s2 = (kt + 2 < NT16) ? kt + 2 : NT16 - 1;
        bf16x8 a0[4], a1[4], b0[4], b1[4];
        LDA(a0, d, 0, 0); LDB(b0, d, 0);
        STAGE_A(kt + 1, s1, 1);
        MM_Q(a0, b0, 0);
        LDA(a1, d, 0, 1);
        STAGE_B(kt + 1, s1, 1);
        MM_Q(a1, b0, 4);
        VMW8; SBAR;
        LDA(a0, d, 1, 0); LDB(b1, d, 1);
        STAGE_A(kt + 2, s2, 0);
        MM_Q(a0, b1, 0);
        LDA(a1, d, 1, 1);
        STAGE_B(kt + 2, s2, 0);
        MM_Q(a1, b1, 4);
        VMW8; SBAR;
    }

    // epilogue: silu(w1-part) * w3-part, pairs (nf=2u, 2u+1) same lane
#pragma unroll
    for (int mf = 0; mf < 8; ++mf)
#pragma unroll
        for (int u = 0; u < 2; ++u)
#pragma unroll
            for (int r = 0; r < 4; ++r) {
                int rowl = wm * 128 + mf * 16 + (lane >> 4) * 4 + r;
                int icol = blockIdx.x * 128 + (wn * 2 + u) * 16 + (lane & 15);
                float v1 = acc[mf][2 * u][r], v3 = acc[mf][2 * u + 1][r];
                float hv = (v1 / (1.f + expf(-v1))) * v3;
                h_bf[(size_t)(bt * 256 + rowl) * I_DIM + icol] = f2bf(hv);
            }
}
#undef STAGE_A
#undef STAGE_B
#undef LDA
#undef LDB

// ---------------- GEMM2: 256x256 tile, 8 waves, same counted-vmcnt pipeline, K=3584 ----------------
// out[t,:] += combine[t,e] * (Hg * W2e^T). A = hb rows (contiguous), B = w2b.
// Grid: 4 col-tiles x MAX_T256 = 288 blocks (~1.1/CU), 56 K-tiles -> best amortization.
// atomicAdd writeback: exactly 2 contributions per element onto zeroed out; deterministic.
__global__ __launch_bounds__(512, 2)
void gemm2_256_kernel(const unsigned short* __restrict__ h_bf,
                      const unsigned short* __restrict__ w2b,
                      const float* __restrict__ combine, float* __restrict__ out,
                      const int* __restrict__ frows, const int* __restrict__ tile_e,
                      const int* __restrict__ tile_valid, const int* __restrict__ ntiles) {
    const int bt = blockIdx.y;
    if (bt >= ntiles[0]) return;
    __shared__ unsigned short lds[65536];
    const int e = tile_e[bt];
    const int valid = tile_valid[bt];
    const int n0 = blockIdx.x * 256;
    const int tid = threadIdx.x;
    const int w = tid >> 6, lane = tid & 63;
    const int wm = w >> 2, wn = w & 3;

    const int srow = tid >> 2;
    const int swcol = 8 * ((tid & 3) ^ ((srow >> 1) & 3));
    const unsigned short* aSrc[2];
    const unsigned short* bSrc[2];
    aSrc[0] = h_bf + (size_t)(bt * 256 + srow) * I_DIM + swcol;
    aSrc[1] = h_bf + (size_t)(bt * 256 + srow + 128) * I_DIM + swcol;
    bSrc[0] = w2b + ((size_t)e * H_DIM + n0 + srow) * I_DIM + swcol;
    bSrc[1] = w2b + ((size_t)e * H_DIM + n0 + srow + 128) * I_DIM + swcol;
    unsigned short* aDst = &lds[w * 512];
    unsigned short* bDst = &lds[32768 + w * 512];

    f32x4 acc[8][4] = {};

#define STAGE_A(DT, ST, KH) do { int kofs_ = (ST) * 64 + (KH) * 32; \
    unsigned short* d_ = aDst + (((DT) & 1) * 2 + (KH)) * 8192; \
    gload16(aSrc[0] + kofs_, d_); gload16(aSrc[1] + kofs_, d_ + 4096); } while (0)
#define STAGE_B(DT, ST, KH) do { int kofs_ = (ST) * 64 + (KH) * 32; \
    unsigned short* d_ = bDst + (((DT) & 1) * 2 + (KH)) * 8192; \
    gload16(bSrc[0] + kofs_, d_); gload16(bSrc[1] + kofs_, d_ + 4096); } while (0)
#define LDA(AF, D, KH, MH) do { \
    _Pragma("unroll") for (int i_ = 0; i_ < 4; ++i_) { \
        int row_ = wm * 128 + ((MH) * 4 + i_) * 16 + (lane & 15); \
        AF[i_] = *(const bf16x8*)&lds[((D) * 2 + (KH)) * 8192 + row_ * 32 + 8 * ((lane >> 4) ^ ((row_ >> 1) & 3))]; } } while (0)
#define LDB(BF, D, KH) do { \
    _Pragma("unroll") for (int i_ = 0; i_ < 4; ++i_) { \
        int row_ = wn * 64 + i_ * 16 + (lane & 15); \
        BF[i_] = *(const bf16x8*)&lds[32768 + ((D) * 2 + (KH)) * 8192 + row_ * 32 + 8 * ((lane >> 4) ^ ((row_ >> 1) & 3))]; } } while (0)

    STAGE_A(0, 0, 0); STAGE_B(0, 0, 0);
    STAGE_A(0, 0, 1); STAGE_B(0, 0, 1);
    STAGE_A(1, 1 < NT2 ? 1 : NT2 - 1, 0); STAGE_B(1, 1 < NT2 ? 1 : NT2 - 1, 0);
    VMW8; SBAR;

    for (int kt = 0; kt < NT2; ++kt) {
        const int d = kt & 1;
        const int s1 = (kt + 1 < NT2) ? kt + 1 : NT2 - 1;
        const int s2 = (kt + 2 < NT2) ? kt + 2 : NT2 - 1;
        bf16x8 a0[4], a1[4], b0[4], b1[4];
        LDA(a0, d, 0, 0); LDB(b0, d, 0);
        STAGE_A(kt + 1, s1, 1);
        MM_Q(a0, b0, 0);
        LDA(a1, d, 0, 1);
        STAGE_B(kt + 1, s1, 1);
        MM_Q(a1, b0, 4);
        VMW8; SBAR;
        LDA(a0, d, 1, 0); LDB(b1, d, 1);
        STAGE_A(kt + 2, s2, 0);
        MM_Q(a0, b1, 0);
        LDA(a1, d, 1, 1);
        STAGE_B(kt + 2, s2, 0);
        MM_Q(a1, b1, 4);
        VMW8; SBAR;
    }

    // epilogue: combine-scaled atomic scatter into out
#pragma unroll
    for (int mf = 0; mf < 8; ++mf)
#pragma unroll
        for (int r = 0; r < 4; ++r) {
            int rowl = wm * 128 + mf * 16 + (lane >> 4) * 4 + r;
            if (rowl < valid) {
                int t = frows[bt * 256 + rowl];
                float cmb = combine[(size_t)t * NEXP + e];
#pragma unroll
                for (int n = 0; n < 4; ++n) {
                    int col = n0 + wn * 64 + n * 16 + (lane & 15);
                    atomicAdd(&out[(size_t)t * H_DIM + col], cmb * acc[mf][n][r]);
                }
            }
        }
}
#undef STAGE_A
#undef STAGE_B
#undef LDA
#undef LDB

// ================= fallback path (R1, verified) =================

__global__ void cvt_x_fb(const float* __restrict__ x, unsigned short* __restrict__ xb) {
    size_t i = (size_t)blockIdx.x * blockDim.x + threadIdx.x;
    const float4* p = (const float4*)x + i * 2;
    float4 a = p[0], b = p[1];
    uint4 o;
    o.x = (unsigned)f2bf(a.x) | ((unsigned)f2bf(a.y) << 16);
    o.y = (unsigned)f2bf(a.z) | ((unsigned)f2bf(a.w) << 16);
    o.z = (unsigned)f2bf(b.x) | ((unsigned)f2bf(b.y) << 16);
    o.w = (unsigned)f2bf(b.z) | ((unsigned)f2bf(b.w) << 16);
    *(uint4*)(xb + i * 8) = o;
}

__global__ void router_fb(const float* __restrict__ x, const float* __restrict__ gw,
                          const float* __restrict__ gb, float* __restrict__ combine,
                          int* __restrict__ rowlist, int* __restrict__ count) {
    int wave = threadIdx.x >> 6, lane = threadIdx.x & 63;
    int t = blockIdx.x * 4 + wave;
    float acc[NEXP];
#pragma unroll
    for (int e = 0; e < NEXP; ++e) acc[e] = 0.f;
    const float4* xr = (const float4*)(x + (size_t)t * H_DIM);
#pragma unroll
    for (int j = 0; j < 4; ++j) {
        int c = j * 64 + lane;
        float4 xv = xr[c];
#pragma unroll
        for (int e = 0; e < NEXP; ++e) {
            float4 gv = ((const float4*)(gw + (size_t)e * H_DIM))[c];
            acc[e] += xv.x * gv.x + xv.y * gv.y + xv.z * gv.z + xv.w * gv.w;
        }
    }
#pragma unroll
    for (int off = 32; off; off >>= 1)
#pragma unroll
        for (int e = 0; e < NEXP; ++e) acc[e] += __shfl_xor(acc[e], off, 64);
    if (lane == 0) {
        float logit[NEXP], mx = -1e30f;
#pragma unroll
        for (int e = 0; e < NEXP; ++e) { logit[e] = acc[e] + gb[e]; mx = fmaxf(mx, logit[e]); }
        float p[NEXP], s = 0.f;
#pragma unroll
        for (int e = 0; e < NEXP; ++e) { p[e] = expf(logit[e] - mx); s += p[e]; }
        float inv = 1.f / s;
#pragma unroll
        for (int e = 0; e < NEXP; ++e) p[e] *= inv;
        int i1 = 0;
#pragma unroll
        for (int e = 1; e < NEXP; ++e) if (p[e] > p[i1]) i1 = e;
        int i2 = -1;
#pragma unroll
        for (int e = 0; e < NEXP; ++e) if (e != i1 && (i2 < 0 || p[e] > p[i2])) i2 = e;
#pragma unroll
        for (int e = 0; e < NEXP; ++e)
            combine[(size_t)t * NEXP + e] = (e == i1 || e == i2) ? p[e] : 0.f;
        int pos1 = atomicAdd(&count[i1], 1); rowlist[i1 * T_TOK + pos1] = t;
        int pos2 = atomicAdd(&count[i2], 1); rowlist[i2 * T_TOK + pos2] = t;
    }
}

__global__ __launch_bounds__(256, 2)
void gemm1_fb(const unsigned short* __restrict__ x_bf,
              const float* __restrict__ w1, const float* __restrict__ w3,
              unsigned short* __restrict__ h_bf,
              const int* __restrict__ rowlist, const int* __restrict__ count, int e) {
    __shared__ unsigned short aT[128 * 64];
    __shared__ unsigned short b1T[128 * 64];
    __shared__ unsigned short b3T[128 * 64];
    __shared__ int rl[128];
    const int cnt = count[e];
    const int r0 = blockIdx.y * 128;
    if (r0 >= cnt) return;
    const int n0 = blockIdx.x * 128;
    const float* __restrict__ w1e = w1 + (size_t)e * I_DIM * H_DIM;
    const float* __restrict__ w3e = w3 + (size_t)e * I_DIM * H_DIM;
    const int tid = threadIdx.x;
    if (tid < 128) {
        int r = r0 + tid;
        rl[tid] = rowlist[e * T_TOK + (r < cnt ? r : 0)];
    }
    __syncthreads();
    const int wave = tid >> 6, lane = tid & 63;
    const int wm = wave >> 1, wn = wave & 1;
    f32x4 acc1[4][4] = {};
    f32x4 acc3[4][4] = {};

    for (int kt = 0; kt < H_DIM / 64; ++kt) {
        const int k0 = kt * 64;
#pragma unroll
        for (int it = 0; it < 4; ++it) {
            int c = it * 256 + tid, row = c >> 3, slot = c & 7;
            uint4 v = *(const uint4*)(x_bf + (size_t)rl[row] * H_DIM + k0 + slot * 8);
            *(uint4*)&aT[row * 64 + ((slot ^ (row & 7)) << 3)] = v;
        }
#pragma unroll
        for (int it = 0; it < 8; ++it) {
            int c = it * 256 + tid, row = c >> 4, cw = c & 15;
            size_t goff = (size_t)(n0 + row) * H_DIM + k0 + cw * 4;
            float4 v1 = *(const float4*)(w1e + goff);
            float4 v3 = *(const float4*)(w3e + goff);
            int offr = row * 64 + (((cw >> 1) ^ (row & 7)) << 3) + (cw & 1) * 4;
            ushort4 p1 = { f2bf(v1.x), f2bf(v1.y), f2bf(v1.z), f2bf(v1.w) };
            ushort4 p3 = { f2bf(v3.x), f2bf(v3.y), f2bf(v3.z), f2bf(v3.w) };
            *(ushort4*)&b1T[offr] = p1;
            *(ushort4*)&b3T[offr] = p3;
        }
        __syncthreads();
#pragma unroll
        for (int ks = 0; ks < 2; ++ks) {
            const int slot = ks * 4 + (lane >> 4);
            bf16x8 af[4], b1f[4], b3f[4];
#pragma unroll
            for (int m = 0; m < 4; ++m) {
                int row = wm * 64 + m * 16 + (lane & 15);
                af[m] = *(const bf16x8*)&aT[row * 64 + ((slot ^ (row & 7)) << 3)];
            }
#pragma unroll
            for (int n = 0; n < 4; ++n) {
                int row = wn * 64 + n * 16 + (lane & 15);
                int offr = row * 64 + ((slot ^ (row & 7)) << 3);
                b1f[n] = *(const bf16x8*)&b1T[offr];
                b3f[n] = *(const bf16x8*)&b3T[offr];
            }
#pragma unroll
            for (int m = 0; m < 4; ++m)
#pragma unroll
                for (int n = 0; n < 4; ++n) {
                    acc1[m][n] = __builtin_amdgcn_mfma_f32_16x16x32_bf16(af[m], b1f[n], acc1[m][n], 0, 0, 0);
                    acc3[m][n] = __builtin_amdgcn_mfma_f32_16x16x32_bf16(af[m], b3f[n], acc3[m][n], 0, 0, 0);
                }
        }
        __syncthreads();
    }
#pragma unroll
    for (int m = 0; m < 4; ++m)
#pragma unroll
        for (int r = 0; r < 4; ++r) {
            int rowl = wm * 64 + m * 16 + (lane >> 4) * 4 + r;
            int ridx = r0 + rowl;
            if (ridx < cnt) {
#pragma unroll
                for (int n = 0; n < 4; ++n) {
                    int col = n0 + wn * 64 + n * 16 + (lane & 15);
                    float v1 = acc1[m][n][r], v3 = acc3[m][n][r];
                    float hv = (v1 / (1.f + expf(-v1))) * v3;
                    h_bf[(size_t)ridx * I_DIM + col] = f2bf(hv);
                }
            }
        }
}

__global__ __launch_bounds__(256, 2)
void gemm2_fb(const unsigned short* __restrict__ h_bf, const float* __restrict__ w2,
              const float* __restrict__ combine, float* __restrict__ out,
              const int* __restrict__ rowlist, const int* __restrict__ count, int e) {
    __shared__ unsigned short aT[128 * 64];
    __shared__ unsigned short bT[128 * 64];
    __shared__ int rl[128];
    const int cnt = count[e];
    const int r0 = blockIdx.y * 128;
    if (r0 >= cnt) return;
    const int n0 = blockIdx.x * 128;
    const float* __restrict__ w2e = w2 + (size_t)e * H_DIM * I_DIM;
    const int tid = threadIdx.x;
    if (tid < 128) {
        int r = r0 + tid;
        rl[tid] = rowlist[e * T_TOK + (r < cnt ? r : 0)];
    }
    __syncthreads();
    const int wave = tid >> 6, lane = tid & 63;
    const int wm = wave >> 1, wn = wave & 1;
    f32x4 acc[4][4] = {};

    for (int kt = 0; kt < I_DIM / 64; ++kt) {
        const int k0 = kt * 64;
#pragma unroll
        for (int it = 0; it < 4; ++it) {
            int c = it * 256 + tid, row = c >> 3, slot = c & 7;
            uint4 v = *(const uint4*)(h_bf + (size_t)(r0 + row) * I_DIM + k0 + slot * 8);
            *(uint4*)&aT[row * 64 + ((slot ^ (row & 7)) << 3)] = v;
        }
#pragma unroll
        for (int it = 0; it < 8; ++it) {
            int c = it * 256 + tid, row = c >> 4, cw = c & 15;
            float4 v = *(const float4*)(w2e + (size_t)(n0 + row) * I_DIM + k0 + cw * 4);
            int offr = row * 64 + (((cw >> 1) ^ (row & 7)) << 3) + (cw & 1) * 4;
            ushort4 p = { f2bf(v.x), f2bf(v.y), f2bf(v.z), f2bf(v.w) };
            *(ushort4*)&bT[offr] = p;
        }
        __syncthreads();
#pragma unroll
        for (int ks = 0; ks < 2; ++ks) {
            const int slot = ks * 4 + (lane >> 4);
            bf16x8 af[4], bfr[4];
#pragma unroll
            for (int m = 0; m < 4; ++m) {
                int row = wm * 64 + m * 16 + (lane & 15);
                af[m] = *(const bf16x8*)&aT[row * 64 + ((slot ^ (row & 7)) << 3)];
            }
#pragma unroll
            for (int n = 0; n < 4; ++n) {
                int row = wn * 64 + n * 16 + (lane & 15);
                bfr[n] = *(const bf16x8*)&bT[row * 64 + ((slot ^ (row & 7)) << 3)];
            }
#pragma unroll
            for (int m = 0; m < 4; ++m)
#pragma unroll
                for (int n = 0; n < 4; ++n)
                    acc[m][n] = __builtin_amdgcn_mfma_f32_16x16x32_bf16(af[m], bfr[n], acc[m][n], 0, 0, 0);
        }
        __syncthreads();
    }
#pragma unroll
    for (int m = 0; m < 4; ++m)
#pragma unroll
        for (int r = 0; r < 4; ++r) {
            int rowl = wm * 64 + m * 16 + (lane >> 4) * 4 + r;
            int ridx = r0 + rowl;
            if (ridx < cnt) {
                int t = rl[rowl];
                float cmb = combine[(size_t)t * NEXP + e];
#pragma unroll
                for (int n = 0; n < 4; ++n) {
                    int col = n0 + wn * 64 + n * 16 + (lane & 15);
                    out[(size_t)t * H_DIM + col] += cmb * acc[m][n][r];
                }
            }
        }
}

// ================= launch =================

extern "C" void kernel_launch(void* const* d_in, const int* in_sizes, int n_in,
                              void* d_out, int out_size, void* d_ws, size_t ws_size,
                              hipStream_t stream) {
    const float* x  = (const float*)d_in[0];
    const float* gw = (const float*)d_in[1];
    const float* gb = (const float*)d_in[2];
    const float* w1 = (const float*)d_in[3];
    const float* w2 = (const float*)d_in[4];
    const float* w3 = (const float*)d_in[5];
    float* out = (float*)d_out;
    char* ws = (char*)d_ws;

    const size_t WELEMS = (size_t)NEXP * I_DIM * H_DIM;      // 29,360,128
    // fast-path layout
    size_t off = 0;
    unsigned short* xb   = (unsigned short*)(ws + off); off += (size_t)T_TOK * H_DIM * 2;        // 16 MB
    unsigned short* w13b = (unsigned short*)(ws + off); off += WELEMS * 2 * 2;                   // 117 MB
    unsigned short* w2b  = (unsigned short*)(ws + off); off += WELEMS * 2;                       // 56 MB
    unsigned short* hb   = (unsigned short*)(ws + off); off += (size_t)MAX_T256 * 256 * I_DIM * 2; // 132 MB
    float* combine       = (float*)(ws + off);          off += (size_t)T_TOK * NEXP * 4;
    int* pair            = (int*)(ws + off);            off += (size_t)T_TOK * 4;
    int* frows           = (int*)(ws + off);            off += (size_t)MAX_T256 * 256 * 4;
    int* tile_e          = (int*)(ws + off);            off += 1024;
    int* tile_valid      = (int*)(ws + off);            off += 1024;
    int* ntiles          = (int*)(ws + off);            off += 1024;
    const size_t WS_NEEDED = off;

    (void)hipMemsetAsync(out, 0, (size_t)T_TOK * H_DIM * sizeof(float), stream);

    if (ws_size >= WS_NEEDED) {
        wcvt13_kernel<<<dim3(2048), dim3(256), 0, stream>>>(w1, w3, w13b, (int)(WELEMS * 2 / 8));
        wcvt_kernel<<<dim3(2048), dim3(256), 0, stream>>>(w2, w2b, (int)(WELEMS / 8));
        router_kernel<<<dim3(T_TOK / 4), dim3(256), 0, stream>>>(x, gw, gb, xb, combine, pair);
        build_lists_kernel<<<dim3(NEXP), dim3(1024), 0, stream>>>(pair, frows, tile_e, tile_valid, ntiles);
        gemm1_256_kernel<<<dim3(I_DIM / 128, MAX_T256), dim3(512), 0, stream>>>(
            xb, w13b, hb, frows, tile_e, ntiles);
        gemm2_256_kernel<<<dim3(H_DIM / 256, MAX_T256), dim3(512), 0, stream>>>(
            hb, w2b, combine, out, frows, tile_e, tile_valid, ntiles);
    } else {
        // fallback: R1 layout (76 MB)
        unsigned short* x_bf    = (unsigned short*)ws;
        unsigned short* h_bf    = (unsigned short*)(ws + 16777216);
        float*          fcomb   = (float*)(ws + 16777216 + 58720256);
        int*            rowlist = (int*)(ws + 16777216 + 58720256 + 262144);
        int*            count   = (int*)(ws + 16777216 + 58720256 + 262144 + 262144);

        (void)hipMemsetAsync(count, 0, NEXP * sizeof(int), stream);
        cvt_x_fb<<<dim3(T_TOK * H_DIM / (256 * 8)), dim3(256), 0, stream>>>(x, x_bf);
        router_fb<<<dim3(T_TOK / 4), dim3(256), 0, stream>>>(x, gw, gb, fcomb, rowlist, count);
        for (int e = 0; e < NEXP; ++e) {
            gemm1_fb<<<dim3(I_DIM / 128, T_TOK / 128), dim3(256), 0, stream>>>(
                x_bf, w1, w3, h_bf, rowlist, count, e);
            gemm2_fb<<<dim3(H_DIM / 128, T_TOK / 128), dim3(256), 0, stream>>>(
                h_bf, w2, fcomb, out, rowlist, count, e);
        }
    }
}

// Round 10
// 629.459 us; speedup vs baseline: 1.0182x; 1.0182x over previous
//
#include <hip/hip_runtime.h>

#define T_TOK 8192
#define H_DIM 1024
#define I_DIM 3584
#define NEXP 8
#define MAX_T256 72            // sum ceil(cnt_e/256) <= 64 + 7, padded
#define NT16 (H_DIM / 64)      // 16 K-tiles for gemm1

typedef __attribute__((ext_vector_type(4))) float f32x4;
typedef __attribute__((ext_vector_type(8))) short bf16x8;

__device__ __forceinline__ unsigned short f2bf(float f) {
    union { float f; unsigned u; } v; v.f = f;
    unsigned r = v.u + 0x7FFFu + ((v.u >> 16) & 1u);
    return (unsigned short)(r >> 16);
}

__device__ __forceinline__ void gload16(const unsigned short* g, unsigned short* l) {
    __builtin_amdgcn_global_load_lds(
        (const __attribute__((address_space(1))) void*)g,
        (__attribute__((address_space(3))) void*)l, 16, 0, 0);
}

#define SBAR asm volatile("s_barrier" ::: "memory")
#define VMW8 asm volatile("s_waitcnt vmcnt(8)" ::: "memory")

// ================= fast path =================

// router: logits -> softmax -> top2; emits pair[t], combine[t][8], and xb (bf16 x)
__global__ void router_kernel(const float* __restrict__ x, const float* __restrict__ gw,
                              const float* __restrict__ gb, unsigned short* __restrict__ xb,
                              float* __restrict__ combine, int* __restrict__ pair) {
    int wave = threadIdx.x >> 6, lane = threadIdx.x & 63;
    int t = blockIdx.x * 4 + wave;
    float acc[NEXP];
#pragma unroll
    for (int e = 0; e < NEXP; ++e) acc[e] = 0.f;
    const float4* xr = (const float4*)(x + (size_t)t * H_DIM);
#pragma unroll
    for (int j = 0; j < 4; ++j) {
        int c = j * 64 + lane;
        float4 xv = xr[c];
        ushort4 o = { f2bf(xv.x), f2bf(xv.y), f2bf(xv.z), f2bf(xv.w) };
        *(ushort4*)(xb + (size_t)t * H_DIM + c * 4) = o;
#pragma unroll
        for (int e = 0; e < NEXP; ++e) {
            float4 gv = ((const float4*)(gw + (size_t)e * H_DIM))[c];
            acc[e] += xv.x * gv.x + xv.y * gv.y + xv.z * gv.z + xv.w * gv.w;
        }
    }
#pragma unroll
    for (int off = 32; off; off >>= 1)
#pragma unroll
        for (int e = 0; e < NEXP; ++e) acc[e] += __shfl_xor(acc[e], off, 64);
    if (lane == 0) {
        float logit[NEXP], mx = -1e30f;
#pragma unroll
        for (int e = 0; e < NEXP; ++e) { logit[e] = acc[e] + gb[e]; mx = fmaxf(mx, logit[e]); }
        float p[NEXP], s = 0.f;
#pragma unroll
        for (int e = 0; e < NEXP; ++e) { p[e] = expf(logit[e] - mx); s += p[e]; }
        float inv = 1.f / s;
#pragma unroll
        for (int e = 0; e < NEXP; ++e) p[e] *= inv;
        int i1 = 0;
#pragma unroll
        for (int e = 1; e < NEXP; ++e) if (p[e] > p[i1]) i1 = e;
        int i2 = -1;
#pragma unroll
        for (int e = 0; e < NEXP; ++e) if (e != i1 && (i2 < 0 || p[e] > p[i2])) i2 = e;
        float4 c0, c1;
        c0.x = (0 == i1 || 0 == i2) ? p[0] : 0.f;  c0.y = (1 == i1 || 1 == i2) ? p[1] : 0.f;
        c0.z = (2 == i1 || 2 == i2) ? p[2] : 0.f;  c0.w = (3 == i1 || 3 == i2) ? p[3] : 0.f;
        c1.x = (4 == i1 || 4 == i2) ? p[4] : 0.f;  c1.y = (5 == i1 || 5 == i2) ? p[5] : 0.f;
        c1.z = (6 == i1 || 6 == i2) ? p[6] : 0.f;  c1.w = (7 == i1 || 7 == i2) ? p[7] : 0.f;
        *(float4*)(combine + (size_t)t * NEXP) = c0;
        *(float4*)(combine + (size_t)t * NEXP + 4) = c1;
        pair[t] = i1 | (i2 << 8);
    }
}

// deterministic, atomic-free list builder; 256-row tile granularity
__global__ void build_lists_kernel(const int* __restrict__ pair, int* __restrict__ frows,
                                   int* __restrict__ tile_e, int* __restrict__ tile_valid,
                                   int* __restrict__ ntiles) {
    const int e = blockIdx.x;
    const int tid = threadIdx.x;
    const int wave = tid >> 6, lane = tid & 63;
    __shared__ int wtot[16][NEXP];
    __shared__ int stot[NEXP];
    __shared__ int wcnt[16];

    int myp[8];
    int tcnt[NEXP] = {0, 0, 0, 0, 0, 0, 0, 0};
#pragma unroll
    for (int c = 0; c < 8; ++c) {
        int pr = pair[c * 1024 + tid];
        myp[c] = pr;
        int e1 = pr & 255, e2 = (pr >> 8) & 255;
#pragma unroll
        for (int j = 0; j < NEXP; ++j) {
            unsigned long long m = __ballot(e1 == j || e2 == j);
            if (lane == 0) tcnt[j] += (int)__popcll(m);
        }
    }
    if (lane == 0) {
#pragma unroll
        for (int j = 0; j < NEXP; ++j) wtot[wave][j] = tcnt[j];
    }
    __syncthreads();
    if (tid < NEXP) {
        int s = 0;
        for (int w = 0; w < 16; ++w) s += wtot[w][tid];
        stot[tid] = s;
    }
    __syncthreads();

    int gbase = 0, tbase = 0, totTiles = 0;
#pragma unroll
    for (int j = 0; j < NEXP; ++j) {
        int tj = (stot[j] + 255) >> 8;
        if (j < e) { gbase += tj << 8; tbase += tj; }
        totTiles += tj;
    }
    const int cnt = stot[e];
    const int mytiles = (cnt + 255) >> 8;

    int base = gbase;
    for (int c = 0; c < 8; ++c) {
        int pr = myp[c];
        bool pred = ((pr & 255) == e) || (((pr >> 8) & 255) == e);
        unsigned long long m = __ballot(pred);
        if (lane == 0) wcnt[wave] = (int)__popcll(m);
        __syncthreads();
        int wb = 0;
        for (int w = 0; w < wave; ++w) wb += wcnt[w];
        int ctot = 0;
        for (int w = 0; w < 16; ++w) ctot += wcnt[w];
        if (pred) {
            int wp = (int)__popcll(m & ((1ull << lane) - 1ull));
            frows[base + wb + wp] = c * 1024 + tid;
        }
        base += ctot;
        __syncthreads();
    }
    if (cnt > 0) {
        int first = frows[gbase];
        for (int p = cnt + tid; p < (mytiles << 8); p += 1024) frows[gbase + p] = first;
        if (tid < mytiles) {
            tile_e[tbase + tid] = e;
            int v = cnt - (tid << 8);
            tile_valid[tbase + tid] = v > 256 ? 256 : v;
        }
    }
    if (e == 0 && tid == 0) ntiles[0] = totTiles;
}

// weights f32 -> bf16 (grid-stride, 8 elems/thread)
__global__ void wcvt_kernel(const float* __restrict__ src, unsigned short* __restrict__ dst, int n8) {
    int stride = gridDim.x * blockDim.x;
    for (int i = blockIdx.x * blockDim.x + threadIdx.x; i < n8; i += stride) {
        const float4* p = (const float4*)src + (size_t)i * 2;
        float4 a = p[0], b = p[1];
        uint4 o;
        o.x = (unsigned)f2bf(a.x) | ((unsigned)f2bf(a.y) << 16);
        o.y = (unsigned)f2bf(a.z) | ((unsigned)f2bf(a.w) << 16);
        o.z = (unsigned)f2bf(b.x) | ((unsigned)f2bf(b.y) << 16);
        o.w = (unsigned)f2bf(b.z) | ((unsigned)f2bf(b.w) << 16);
        *(uint4*)(dst + (size_t)i * 8) = o;
    }
}

// w1,w3 f32 -> interleaved bf16 w13i[e][7168][1024]:
// row r: s=r&31, rg=r>>5; s<16 -> w1 row rg*16+s ; s>=16 -> w3 row rg*16+s-16
__global__ void wcvt13_kernel(const float* __restrict__ w1, const float* __restrict__ w3,
                              unsigned short* __restrict__ dst, int n8) {
    int stride = gridDim.x * blockDim.x;
    for (int g = blockIdx.x * blockDim.x + threadIdx.x; g < n8; g += stride) {
        int col = (g & 127) * 8;
        int er = g >> 7;
        int r = er % 7168;
        int e = er / 7168;
        int s = r & 31, rg = r >> 5;
        const float* src = (s < 16)
            ? (w1 + ((size_t)e * I_DIM + rg * 16 + s) * H_DIM + col)
            : (w3 + ((size_t)e * I_DIM + rg * 16 + (s - 16)) * H_DIM + col);
        float4 a = *(const float4*)src;
        float4 b = *(const float4*)(src + 4);
        uint4 o;
        o.x = (unsigned)f2bf(a.x) | ((unsigned)f2bf(a.y) << 16);
        o.y = (unsigned)f2bf(a.z) | ((unsigned)f2bf(a.w) << 16);
        o.z = (unsigned)f2bf(b.x) | ((unsigned)f2bf(b.y) << 16);
        o.w = (unsigned)f2bf(b.z) | ((unsigned)f2bf(b.w) << 16);
        *(uint4*)(dst + (size_t)g * 8) = o;
    }
}

// shared MFMA cluster macro (16 MFMAs, setprio-wrapped)
#define MM_Q(AF, BF, MB) do { \
    __builtin_amdgcn_s_setprio(1); \
    _Pragma("unroll") for (int i_ = 0; i_ < 4; ++i_) \
    { _Pragma("unroll") for (int n_ = 0; n_ < 4; ++n_) \
        acc[MB + i_][n_] = __builtin_amdgcn_mfma_f32_16x16x32_bf16(AF[i_], BF[n_], acc[MB + i_][n_], 0, 0, 0); } \
    __builtin_amdgcn_s_setprio(0); } while (0)

// ---------------- GEMM1: 256x256 tile, 8 waves, counted-vmcnt pipeline, 2 barriers/K-tile ----------------
// R8-verified structure. Grid SWAPPED to (MAX_T256, I_DIM/128): bt = blockIdx.x
// (fastest-varying) so XCD round-robin groups same-column-panel blocks per XCD ->
// the 512KB B-panel becomes L2-resident per XCD (T1 L2-locality).
__global__ __launch_bounds__(512, 2)
void gemm1_256_kernel(const unsigned short* __restrict__ xb,
                      const unsigned short* __restrict__ w13b,
                      unsigned short* __restrict__ h_bf,
                      const int* __restrict__ frows, const int* __restrict__ tile_e,
                      const int* __restrict__ ntiles) {
    const int bt = blockIdx.x;
    if (bt >= ntiles[0]) return;
    __shared__ unsigned short lds[65536];   // A at 0, B at elem 32768; halves of 8192 elems
    const int e = tile_e[bt];
    const int n0 = blockIdx.y * 256;
    const int tid = threadIdx.x;
    const int w = tid >> 6, lane = tid & 63;
    const int wm = w >> 2, wn = w & 3;

    const int srow = tid >> 2;
    const int swcol = 8 * ((tid & 3) ^ ((srow >> 1) & 3));
    const unsigned short* aSrc[2];
    const unsigned short* bSrc[2];
    aSrc[0] = xb + (size_t)frows[bt * 256 + srow] * H_DIM + swcol;
    aSrc[1] = xb + (size_t)frows[bt * 256 + srow + 128] * H_DIM + swcol;
    bSrc[0] = w13b + ((size_t)e * 7168 + n0 + srow) * H_DIM + swcol;
    bSrc[1] = w13b + ((size_t)e * 7168 + n0 + srow + 128) * H_DIM + swcol;
    unsigned short* aDst = &lds[w * 512];
    unsigned short* bDst = &lds[32768 + w * 512];

    f32x4 acc[8][4] = {};

#define STAGE_A(DT, ST, KH) do { int kofs_ = (ST) * 64 + (KH) * 32; \
    unsigned short* d_ = aDst + (((DT) & 1) * 2 + (KH)) * 8192; \
    gload16(aSrc[0] + kofs_, d_); gload16(aSrc[1] + kofs_, d_ + 4096); } while (0)
#define STAGE_B(DT, ST, KH) do { int kofs_ = (ST) * 64 + (KH) * 32; \
    unsigned short* d_ = bDst + (((DT) & 1) * 2 + (KH)) * 8192; \
    gload16(bSrc[0] + kofs_, d_); gload16(bSrc[1] + kofs_, d_ + 4096); } while (0)
#define LDA(AF, D, KH, MH) do { \
    _Pragma("unroll") for (int i_ = 0; i_ < 4; ++i_) { \
        int row_ = wm * 128 + ((MH) * 4 + i_) * 16 + (lane & 15); \
        AF[i_] = *(const bf16x8*)&lds[((D) * 2 + (KH)) * 8192 + row_ * 32 + 8 * ((lane >> 4) ^ ((row_ >> 1) & 3))]; } } while (0)
#define LDB(BF, D, KH) do { \
    _Pragma("unroll") for (int i_ = 0; i_ < 4; ++i_) { \
        int row_ = wn * 64 + i_ * 16 + (lane & 15); \
        BF[i_] = *(const bf16x8*)&lds[32768 + ((D) * 2 + (KH)) * 8192 + row_ * 32 + 8 * ((lane >> 4) ^ ((row_ >> 1) & 3))]; } } while (0)

    STAGE_A(0, 0, 0); STAGE_B(0, 0, 0);
    STAGE_A(0, 0, 1); STAGE_B(0, 0, 1);
    STAGE_A(1, 1 < NT16 ? 1 : NT16 - 1, 0); STAGE_B(1, 1 < NT16 ? 1 : NT16 - 1, 0);
    VMW8; SBAR;

    for (int kt = 0; kt < NT16; ++kt) {
        const int d = kt & 1;
        const int s1 = (kt + 1 < NT16) ? kt + 1 : NT16 - 1;
        const int s2 = (kt + 2 < NT16) ? kt + 2 : NT16 - 1;
        bf16x8 a0[4], a1[4], b0[4], b1[4];
        LDA(a0, d, 0, 0); LDB(b0, d, 0);
        STAGE_A(kt + 1, s1, 1);
        MM_Q(a0, b0, 0);
        LDA(a1, d, 0, 1);
        STAGE_B(kt + 1, s1, 1);
        MM_Q(a1, b0, 4);
        VMW8; SBAR;
        LDA(a0, d, 1, 0); LDB(b1, d, 1);
        STAGE_A(kt + 2, s2, 0);
        MM_Q(a0, b1, 0);
        LDA(a1, d, 1, 1);
        STAGE_B(kt + 2, s2, 0);
        MM_Q(a1, b1, 4);
        VMW8; SBAR;
    }

    // epilogue: silu(w1-part) * w3-part, pairs (nf=2u, 2u+1) same lane
#pragma unroll
    for (int mf = 0; mf < 8; ++mf)
#pragma unroll
        for (int u = 0; u < 2; ++u)
#pragma unroll
            for (int r = 0; r < 4; ++r) {
                int rowl = wm * 128 + mf * 16 + (lane >> 4) * 4 + r;
                int icol = blockIdx.y * 128 + (wn * 2 + u) * 16 + (lane & 15);
                float v1 = acc[mf][2 * u][r], v3 = acc[mf][2 * u + 1][r];
                float hv = (v1 / (1.f + expf(-v1))) * v3;
                h_bf[(size_t)(bt * 256 + rowl) * I_DIM + icol] = f2bf(hv);
            }
}
#undef STAGE_A
#undef STAGE_B
#undef LDA
#undef LDB

// GEMM2 (flat, 128x128, R8-verified): out[t,:] += combine[t,e] * (Hg * W2e^T)
// Grid SWAPPED to (MAX_T256*2, H_DIM/128): bt fastest -> same w2 column-panel
// (917KB) L2-resident per XCD. atomicAdd writeback (2 contributions per element
// onto zeroed out; f32 add commutes => deterministic).
__global__ __launch_bounds__(256, 2)
void gemm2_kernel(const unsigned short* __restrict__ h_bf, const unsigned short* __restrict__ w2b,
                  const float* __restrict__ combine, float* __restrict__ out,
                  const int* __restrict__ frows, const int* __restrict__ tile_e,
                  const int* __restrict__ tile_valid, const int* __restrict__ ntiles) {
    const int bt = blockIdx.x;            // 128-row granularity
    const int t256 = bt >> 1;
    if (t256 >= ntiles[0]) return;
    __shared__ unsigned short aT[128 * 64];
    __shared__ unsigned short bT[128 * 64];
    const int e = tile_e[t256];
    int valid = tile_valid[t256] - (bt & 1) * 128;
    if (valid > 128) valid = 128;
    if (valid <= 0) return;
    const int n0 = blockIdx.y * 128;
    const int tid = threadIdx.x, wave = tid >> 6, lane = tid & 63;
    const int wm = wave >> 1, wn = wave & 1;

    const int sslot = (lane & 7) ^ (lane >> 3);
    const unsigned short *aS[4], *bS[4];
    unsigned short *aD[4], *bD[4];
#pragma unroll
    for (int i = 0; i < 4; ++i) {
        int rowl = wave * 32 + i * 8 + (lane >> 3);
        int c8 = sslot * 8;
        aS[i] = h_bf + (size_t)(bt * 128 + rowl) * I_DIM + c8;
        bS[i] = w2b + ((size_t)e * H_DIM + n0 + rowl) * I_DIM + c8;
        int r0l = wave * 32 + i * 8;
        aD[i] = &aT[r0l * 64]; bD[i] = &bT[r0l * 64];
    }
    f32x4 acc[4][4] = {};

    for (int kt = 0; kt < I_DIM / 64; ++kt) {
#pragma unroll
        for (int i = 0; i < 4; ++i) {
            gload16(aS[i], aD[i]);
            gload16(bS[i], bD[i]);
            aS[i] += 64; bS[i] += 64;
        }
        __syncthreads();
#pragma unroll
        for (int ks = 0; ks < 2; ++ks) {
            const int slot = ks * 4 + (lane >> 4);
            bf16x8 af[4], bfr[4];
#pragma unroll
            for (int m = 0; m < 4; ++m) {
                int row = wm * 64 + m * 16 + (lane & 15);
                af[m] = *(const bf16x8*)&aT[row * 64 + ((slot ^ (row & 7)) << 3)];
            }
#pragma unroll
            for (int n = 0; n < 4; ++n) {
                int row = wn * 64 + n * 16 + (lane & 15);
                bfr[n] = *(const bf16x8*)&bT[row * 64 + ((slot ^ (row & 7)) << 3)];
            }
#pragma unroll
            for (int m = 0; m < 4; ++m)
#pragma unroll
                for (int n = 0; n < 4; ++n)
                    acc[m][n] = __builtin_amdgcn_mfma_f32_16x16x32_bf16(af[m], bfr[n], acc[m][n], 0, 0, 0);
        }
        __syncthreads();
    }
#pragma unroll
    for (int m = 0; m < 4; ++m)
#pragma unroll
        for (int r = 0; r < 4; ++r) {
            int rowl = wm * 64 + m * 16 + (lane >> 4) * 4 + r;
            if (rowl < valid) {
                int t = frows[t256 * 256 + (bt & 1) * 128 + rowl];
                float cmb = combine[(size_t)t * NEXP + e];
#pragma unroll
                for (int n = 0; n < 4; ++n) {
                    int col = n0 + wn * 64 + n * 16 + (lane & 15);
                    atomicAdd(&out[(size_t)t * H_DIM + col], cmb * acc[m][n][r]);
                }
            }
        }
}

// ================= fallback path (R1, verified) =================

__global__ void cvt_x_fb(const float* __restrict__ x, unsigned short* __restrict__ xb) {
    size_t i = (size_t)blockIdx.x * blockDim.x + threadIdx.x;
    const float4* p = (const float4*)x + i * 2;
    float4 a = p[0], b = p[1];
    uint4 o;
    o.x = (unsigned)f2bf(a.x) | ((unsigned)f2bf(a.y) << 16);
    o.y = (unsigned)f2bf(a.z) | ((unsigned)f2bf(a.w) << 16);
    o.z = (unsigned)f2bf(b.x) | ((unsigned)f2bf(b.y) << 16);
    o.w = (unsigned)f2bf(b.z) | ((unsigned)f2bf(b.w) << 16);
    *(uint4*)(xb + i * 8) = o;
}

__global__ void router_fb(const float* __restrict__ x, const float* __restrict__ gw,
                          const float* __restrict__ gb, float* __restrict__ combine,
                          int* __restrict__ rowlist, int* __restrict__ count) {
    int wave = threadIdx.x >> 6, lane = threadIdx.x & 63;
    int t = blockIdx.x * 4 + wave;
    float acc[NEXP];
#pragma unroll
    for (int e = 0; e < NEXP; ++e) acc[e] = 0.f;
    const float4* xr = (const float4*)(x + (size_t)t * H_DIM);
#pragma unroll
    for (int j = 0; j < 4; ++j) {
        int c = j * 64 + lane;
        float4 xv = xr[c];
#pragma unroll
        for (int e = 0; e < NEXP; ++e) {
            float4 gv = ((const float4*)(gw + (size_t)e * H_DIM))[c];
            acc[e] += xv.x * gv.x + xv.y * gv.y + xv.z * gv.z + xv.w * gv.w;
        }
    }
#pragma unroll
    for (int off = 32; off; off >>= 1)
#pragma unroll
        for (int e = 0; e < NEXP; ++e) acc[e] += __shfl_xor(acc[e], off, 64);
    if (lane == 0) {
        float logit[NEXP], mx = -1e30f;
#pragma unroll
        for (int e = 0; e < NEXP; ++e) { logit[e] = acc[e] + gb[e]; mx = fmaxf(mx, logit[e]); }
        float p[NEXP], s = 0.f;
#pragma unroll
        for (int e = 0; e < NEXP; ++e) { p[e] = expf(logit[e] - mx); s += p[e]; }
        float inv = 1.f / s;
#pragma unroll
        for (int e = 0; e < NEXP; ++e) p[e] *= inv;
        int i1 = 0;
#pragma unroll
        for (int e = 1; e < NEXP; ++e) if (p[e] > p[i1]) i1 = e;
        int i2 = -1;
#pragma unroll
        for (int e = 0; e < NEXP; ++e) if (e != i1 && (i2 < 0 || p[e] > p[i2])) i2 = e;
#pragma unroll
        for (int e = 0; e < NEXP; ++e)
            combine[(size_t)t * NEXP + e] = (e == i1 || e == i2) ? p[e] : 0.f;
        int pos1 = atomicAdd(&count[i1], 1); rowlist[i1 * T_TOK + pos1] = t;
        int pos2 = atomicAdd(&count[i2], 1); rowlist[i2 * T_TOK + pos2] = t;
    }
}

__global__ __launch_bounds__(256, 2)
void gemm1_fb(const unsigned short* __restrict__ x_bf,
              const float* __restrict__ w1, const float* __restrict__ w3,
              unsigned short* __restrict__ h_bf,
              const int* __restrict__ rowlist, const int* __restrict__ count, int e) {
    __shared__ unsigned short aT[128 * 64];
    __shared__ unsigned short b1T[128 * 64];
    __shared__ unsigned short b3T[128 * 64];
    __shared__ int rl[128];
    const int cnt = count[e];
    const int r0 = blockIdx.y * 128;
    if (r0 >= cnt) return;
    const int n0 = blockIdx.x * 128;
    const float* __restrict__ w1e = w1 + (size_t)e * I_DIM * H_DIM;
    const float* __restrict__ w3e = w3 + (size_t)e * I_DIM * H_DIM;
    const int tid = threadIdx.x;
    if (tid < 128) {
        int r = r0 + tid;
        rl[tid] = rowlist[e * T_TOK + (r < cnt ? r : 0)];
    }
    __syncthreads();
    const int wave = tid >> 6, lane = tid & 63;
    const int wm = wave >> 1, wn = wave & 1;
    f32x4 acc1[4][4] = {};
    f32x4 acc3[4][4] = {};

    for (int kt = 0; kt < H_DIM / 64; ++kt) {
        const int k0 = kt * 64;
#pragma unroll
        for (int it = 0; it < 4; ++it) {
            int c = it * 256 + tid, row = c >> 3, slot = c & 7;
            uint4 v = *(const uint4*)(x_bf + (size_t)rl[row] * H_DIM + k0 + slot * 8);
            *(uint4*)&aT[row * 64 + ((slot ^ (row & 7)) << 3)] = v;
        }
#pragma unroll
        for (int it = 0; it < 8; ++it) {
            int c = it * 256 + tid, row = c >> 4, cw = c & 15;
            size_t goff = (size_t)(n0 + row) * H_DIM + k0 + cw * 4;
            float4 v1 = *(const float4*)(w1e + goff);
            float4 v3 = *(const float4*)(w3e + goff);
            int offr = row * 64 + (((cw >> 1) ^ (row & 7)) << 3) + (cw & 1) * 4;
            ushort4 p1 = { f2bf(v1.x), f2bf(v1.y), f2bf(v1.z), f2bf(v1.w) };
            ushort4 p3 = { f2bf(v3.x), f2bf(v3.y), f2bf(v3.z), f2bf(v3.w) };
            *(ushort4*)&b1T[offr] = p1;
            *(ushort4*)&b3T[offr] = p3;
        }
        __syncthreads();
#pragma unroll
        for (int ks = 0; ks < 2; ++ks) {
            const int slot = ks * 4 + (lane >> 4);
            bf16x8 af[4], b1f[4], b3f[4];
#pragma unroll
            for (int m = 0; m < 4; ++m) {
                int row = wm * 64 + m * 16 + (lane & 15);
                af[m] = *(const bf16x8*)&aT[row * 64 + ((slot ^ (row & 7)) << 3)];
            }
#pragma unroll
            for (int n = 0; n < 4; ++n) {
                int row = wn * 64 + n * 16 + (lane & 15);
                int offr = row * 64 + ((slot ^ (row & 7)) << 3);
                b1f[n] = *(const bf16x8*)&b1T[offr];
                b3f[n] = *(const bf16x8*)&b3T[offr];
            }
#pragma unroll
            for (int m = 0; m < 4; ++m)
#pragma unroll
                for (int n = 0; n < 4; ++n) {
                    acc1[m][n] = __builtin_amdgcn_mfma_f32_16x16x32_bf16(af[m], b1f[n], acc1[m][n], 0, 0, 0);
                    acc3[m][n] = __builtin_amdgcn_mfma_f32_16x16x32_bf16(af[m], b3f[n], acc3[m][n], 0, 0, 0);
                }
        }
        __syncthreads();
    }
#pragma unroll
    for (int m = 0; m < 4; ++m)
#pragma unroll
        for (int r = 0; r < 4; ++r) {
            int rowl = wm * 64 + m * 16 + (lane >> 4) * 4 + r;
            int ridx = r0 + rowl;
            if (ridx < cnt) {
#pragma unroll
                for (int n = 0; n < 4; ++n) {
                    int col = n0 + wn * 64 + n * 16 + (lane & 15);
                    float v1 = acc1[m][n][r], v3 = acc3[m][n][r];
                    float hv = (v1 / (1.f + expf(-v1))) * v3;
                    h_bf[(size_t)ridx * I_DIM + col] = f2bf(hv);
                }
            }
        }
}

__global__ __launch_bounds__(256, 2)
void gemm2_fb(const unsigned short* __restrict__ h_bf, const float* __restrict__ w2,
              const float* __restrict__ combine, float* __restrict__ out,
              const int* __restrict__ rowlist, const int* __restrict__ count, int e) {
    __shared__ unsigned short aT[128 * 64];
    __shared__ unsigned short bT[128 * 64];
    __shared__ int rl[128];
    const int cnt = count[e];
    const int r0 = blockIdx.y * 128;
    if (r0 >= cnt) return;
    const int n0 = blockIdx.x * 128;
    const float* __restrict__ w2e = w2 + (size_t)e * H_DIM * I_DIM;
    const int tid = threadIdx.x;
    if (tid < 128) {
        int r = r0 + tid;
        rl[tid] = rowlist[e * T_TOK + (r < cnt ? r : 0)];
    }
    __syncthreads();
    const int wave = tid >> 6, lane = tid & 63;
    const int wm = wave >> 1, wn = wave & 1;
    f32x4 acc[4][4] = {};

    for (int kt = 0; kt < I_DIM / 64; ++kt) {
        const int k0 = kt * 64;
#pragma unroll
        for (int it = 0; it < 4; ++it) {
            int c = it * 256 + tid, row = c >> 3, slot = c & 7;
            uint4 v = *(const uint4*)(h_bf + (size_t)(r0 + row) * I_DIM + k0 + slot * 8);
            *(uint4*)&aT[row * 64 + ((slot ^ (row & 7)) << 3)] = v;
        }
#pragma unroll
        for (int it = 0; it < 8; ++it) {
            int c = it * 256 + tid, row = c >> 4, cw = c & 15;
            float4 v = *(const float4*)(w2e + (size_t)(n0 + row) * I_DIM + k0 + cw * 4);
            int offr = row * 64 + (((cw >> 1) ^ (row & 7)) << 3) + (cw & 1) * 4;
            ushort4 p = { f2bf(v.x), f2bf(v.y), f2bf(v.z), f2bf(v.w) };
            *(ushort4*)&bT[offr] = p;
        }
        __syncthreads();
#pragma unroll
        for (int ks = 0; ks < 2; ++ks) {
            const int slot = ks * 4 + (lane >> 4);
            bf16x8 af[4], bfr[4];
#pragma unroll
            for (int m = 0; m < 4; ++m) {
                int row = wm * 64 + m * 16 + (lane & 15);
                af[m] = *(const bf16x8*)&aT[row * 64 + ((slot ^ (row & 7)) << 3)];
            }
#pragma unroll
            for (int n = 0; n < 4; ++n) {
                int row = wn * 64 + n * 16 + (lane & 15);
                bfr[n] = *(const bf16x8*)&bT[row * 64 + ((slot ^ (row & 7)) << 3)];
            }
#pragma unroll
            for (int m = 0; m < 4; ++m)
#pragma unroll
                for (int n = 0; n < 4; ++n)
                    acc[m][n] = __builtin_amdgcn_mfma_f32_16x16x32_bf16(af[m], bfr[n], acc[m][n], 0, 0, 0);
        }
        __syncthreads();
    }
#pragma unroll
    for (int m = 0; m < 4; ++m)
#pragma unroll
        for (int r = 0; r < 4; ++r) {
            int rowl = wm * 64 + m * 16 + (lane >> 4) * 4 + r;
            int ridx = r0 + rowl;
            if (ridx < cnt) {
                int t = rl[rowl];
                float cmb = combine[(size_t)t * NEXP + e];
#pragma unroll
                for (int n = 0; n < 4; ++n) {
                    int col = n0 + wn * 64 + n * 16 + (lane & 15);
                    out[(size_t)t * H_DIM + col] += cmb * acc[m][n][r];
                }
            }
        }
}

// ================= launch =================

extern "C" void kernel_launch(void* const* d_in, const int* in_sizes, int n_in,
                              void* d_out, int out_size, void* d_ws, size_t ws_size,
                              hipStream_t stream) {
    const float* x  = (const float*)d_in[0];
    const float* gw = (const float*)d_in[1];
    const float* gb = (const float*)d_in[2];
    const float* w1 = (const float*)d_in[3];
    const float* w2 = (const float*)d_in[4];
    const float* w3 = (const float*)d_in[5];
    float* out = (float*)d_out;
    char* ws = (char*)d_ws;

    const size_t WELEMS = (size_t)NEXP * I_DIM * H_DIM;      // 29,360,128
    // fast-path layout
    size_t off = 0;
    unsigned short* xb   = (unsigned short*)(ws + off); off += (size_t)T_TOK * H_DIM * 2;        // 16 MB
    unsigned short* w13b = (unsigned short*)(ws + off); off += WELEMS * 2 * 2;                   // 117 MB
    unsigned short* w2b  = (unsigned short*)(ws + off); off += WELEMS * 2;                       // 56 MB
    unsigned short* hb   = (unsigned short*)(ws + off); off += (size_t)MAX_T256 * 256 * I_DIM * 2; // 132 MB
    float* combine       = (float*)(ws + off);          off += (size_t)T_TOK * NEXP * 4;
    int* pair            = (int*)(ws + off);            off += (size_t)T_TOK * 4;
    int* frows           = (int*)(ws + off);            off += (size_t)MAX_T256 * 256 * 4;
    int* tile_e          = (int*)(ws + off);            off += 1024;
    int* tile_valid      = (int*)(ws + off);            off += 1024;
    int* ntiles          = (int*)(ws + off);            off += 1024;
    const size_t WS_NEEDED = off;

    (void)hipMemsetAsync(out, 0, (size_t)T_TOK * H_DIM * sizeof(float), stream);

    if (ws_size >= WS_NEEDED) {
        wcvt13_kernel<<<dim3(2048), dim3(256), 0, stream>>>(w1, w3, w13b, (int)(WELEMS * 2 / 8));
        wcvt_kernel<<<dim3(2048), dim3(256), 0, stream>>>(w2, w2b, (int)(WELEMS / 8));
        router_kernel<<<dim3(T_TOK / 4), dim3(256), 0, stream>>>(x, gw, gb, xb, combine, pair);
        build_lists_kernel<<<dim3(NEXP), dim3(1024), 0, stream>>>(pair, frows, tile_e, tile_valid, ntiles);
        gemm1_256_kernel<<<dim3(MAX_T256, I_DIM / 128), dim3(512), 0, stream>>>(
            xb, w13b, hb, frows, tile_e, ntiles);
        gemm2_kernel<<<dim3(MAX_T256 * 2, H_DIM / 128), dim3(256), 0, stream>>>(
            hb, w2b, combine, out, frows, tile_e, tile_valid, ntiles);
    } else {
        // fallback: R1 layout (76 MB)
        unsigned short* x_bf    = (unsigned short*)ws;
        unsigned short* h_bf    = (unsigned short*)(ws + 16777216);
        float*          fcomb   = (float*)(ws + 16777216 + 58720256);
        int*            rowlist = (int*)(ws + 16777216 + 58720256 + 262144);
        int*            count   = (int*)(ws + 16777216 + 58720256 + 262144 + 262144);

        (void)hipMemsetAsync(count, 0, NEXP * sizeof(int), stream);
        cvt_x_fb<<<dim3(T_TOK * H_DIM / (256 * 8)), dim3(256), 0, stream>>>(x, x_bf);
        router_fb<<<dim3(T_TOK / 4), dim3(256), 0, stream>>>(x, gw, gb, fcomb, rowlist, count);
        for (int e = 0; e < NEXP; ++e) {
            gemm1_fb<<<dim3(I_DIM / 128, T_TOK / 128), dim3(256), 0, stream>>>(
                x_bf, w1, w3, h_bf, rowlist, count, e);
            gemm2_fb<<<dim3(H_DIM / 128, T_TOK / 128), dim3(256), 0, stream>>>(
                h_bf, w2, fcomb, out, rowlist, count, e);
        }
    }
}

// Round 11
// 602.649 us; speedup vs baseline: 1.0635x; 1.0445x over previous
//
#include <hip/hip_runtime.h>

#define T_TOK 8192
#define H_DIM 1024
#define I_DIM 3584
#define NEXP 8
#define MAX_TILES 136          // sum ceil(cnt_e/128) <= 128 + 7, padded

typedef __attribute__((ext_vector_type(4))) float f32x4;
typedef __attribute__((ext_vector_type(8))) short bf16x8;

__device__ __forceinline__ unsigned short f2bf(float f) {
    union { float f; unsigned u; } v; v.f = f;
    unsigned r = v.u + 0x7FFFu + ((v.u >> 16) & 1u);
    return (unsigned short)(r >> 16);
}

__device__ __forceinline__ void gload16(const unsigned short* g, unsigned short* l) {
    __builtin_amdgcn_global_load_lds(
        (const __attribute__((address_space(1))) void*)g,
        (__attribute__((address_space(3))) void*)l, 16, 0, 0);
}

// ================= fast path =================

// router: logits -> softmax -> top2; emits pair[t], combine[t][8], and xb (bf16 x)
__global__ void router_kernel(const float* __restrict__ x, const float* __restrict__ gw,
                              const float* __restrict__ gb, unsigned short* __restrict__ xb,
                              float* __restrict__ combine, int* __restrict__ pair) {
    int wave = threadIdx.x >> 6, lane = threadIdx.x & 63;
    int t = blockIdx.x * 4 + wave;
    float acc[NEXP];
#pragma unroll
    for (int e = 0; e < NEXP; ++e) acc[e] = 0.f;
    const float4* xr = (const float4*)(x + (size_t)t * H_DIM);
#pragma unroll
    for (int j = 0; j < 4; ++j) {
        int c = j * 64 + lane;
        float4 xv = xr[c];
        ushort4 o = { f2bf(xv.x), f2bf(xv.y), f2bf(xv.z), f2bf(xv.w) };
        *(ushort4*)(xb + (size_t)t * H_DIM + c * 4) = o;
#pragma unroll
        for (int e = 0; e < NEXP; ++e) {
            float4 gv = ((const float4*)(gw + (size_t)e * H_DIM))[c];
            acc[e] += xv.x * gv.x + xv.y * gv.y + xv.z * gv.z + xv.w * gv.w;
        }
    }
#pragma unroll
    for (int off = 32; off; off >>= 1)
#pragma unroll
        for (int e = 0; e < NEXP; ++e) acc[e] += __shfl_xor(acc[e], off, 64);
    if (lane == 0) {
        float logit[NEXP], mx = -1e30f;
#pragma unroll
        for (int e = 0; e < NEXP; ++e) { logit[e] = acc[e] + gb[e]; mx = fmaxf(mx, logit[e]); }
        float p[NEXP], s = 0.f;
#pragma unroll
        for (int e = 0; e < NEXP; ++e) { p[e] = expf(logit[e] - mx); s += p[e]; }
        float inv = 1.f / s;
#pragma unroll
        for (int e = 0; e < NEXP; ++e) p[e] *= inv;
        int i1 = 0;
#pragma unroll
        for (int e = 1; e < NEXP; ++e) if (p[e] > p[i1]) i1 = e;
        int i2 = -1;
#pragma unroll
        for (int e = 0; e < NEXP; ++e) if (e != i1 && (i2 < 0 || p[e] > p[i2])) i2 = e;
        float4 c0, c1;
        c0.x = (0 == i1 || 0 == i2) ? p[0] : 0.f;  c0.y = (1 == i1 || 1 == i2) ? p[1] : 0.f;
        c0.z = (2 == i1 || 2 == i2) ? p[2] : 0.f;  c0.w = (3 == i1 || 3 == i2) ? p[3] : 0.f;
        c1.x = (4 == i1 || 4 == i2) ? p[4] : 0.f;  c1.y = (5 == i1 || 5 == i2) ? p[5] : 0.f;
        c1.z = (6 == i1 || 6 == i2) ? p[6] : 0.f;  c1.w = (7 == i1 || 7 == i2) ? p[7] : 0.f;
        *(float4*)(combine + (size_t)t * NEXP) = c0;
        *(float4*)(combine + (size_t)t * NEXP + 4) = c1;
        pair[t] = i1 | (i2 << 8);
    }
}

// deterministic, atomic-free list builder: 8 blocks (one per expert), 1024 threads.
__global__ void build_lists_kernel(const int* __restrict__ pair, int* __restrict__ frows,
                                   int* __restrict__ tile_e, int* __restrict__ tile_valid,
                                   int* __restrict__ ntiles) {
    const int e = blockIdx.x;
    const int tid = threadIdx.x;
    const int wave = tid >> 6, lane = tid & 63;
    __shared__ int wtot[16][NEXP];
    __shared__ int stot[NEXP];
    __shared__ int wcnt[16];

    int myp[8];
    int tcnt[NEXP] = {0, 0, 0, 0, 0, 0, 0, 0};
#pragma unroll
    for (int c = 0; c < 8; ++c) {
        int pr = pair[c * 1024 + tid];
        myp[c] = pr;
        int e1 = pr & 255, e2 = (pr >> 8) & 255;
#pragma unroll
        for (int j = 0; j < NEXP; ++j) {
            unsigned long long m = __ballot(e1 == j || e2 == j);
            if (lane == 0) tcnt[j] += (int)__popcll(m);
        }
    }
    if (lane == 0) {
#pragma unroll
        for (int j = 0; j < NEXP; ++j) wtot[wave][j] = tcnt[j];
    }
    __syncthreads();
    if (tid < NEXP) {
        int s = 0;
        for (int w = 0; w < 16; ++w) s += wtot[w][tid];
        stot[tid] = s;
    }
    __syncthreads();

    int gbase = 0, tbase = 0, totTiles = 0;
#pragma unroll
    for (int j = 0; j < NEXP; ++j) {
        int tj = (stot[j] + 127) >> 7;
        if (j < e) { gbase += tj << 7; tbase += tj; }
        totTiles += tj;
    }
    const int cnt = stot[e];
    const int mytiles = (cnt + 127) >> 7;

    int base = gbase;
    for (int c = 0; c < 8; ++c) {
        int pr = myp[c];
        bool pred = ((pr & 255) == e) || (((pr >> 8) & 255) == e);
        unsigned long long m = __ballot(pred);
        if (lane == 0) wcnt[wave] = (int)__popcll(m);
        __syncthreads();
        int wb = 0;
        for (int w = 0; w < wave; ++w) wb += wcnt[w];
        int ctot = 0;
        for (int w = 0; w < 16; ++w) ctot += wcnt[w];
        if (pred) {
            int wp = (int)__popcll(m & ((1ull << lane) - 1ull));
            frows[base + wb + wp] = c * 1024 + tid;
        }
        base += ctot;
        __syncthreads();
    }
    if (cnt > 0) {
        int first = frows[gbase];
        for (int p = cnt + tid; p < (mytiles << 7); p += 1024) frows[gbase + p] = first;
        if (tid < mytiles) {
            tile_e[tbase + tid] = e;
            int v = cnt - (tid << 7);
            tile_valid[tbase + tid] = v > 128 ? 128 : v;
        }
    }
    if (e == 0 && tid == 0) ntiles[0] = totTiles;
}

// merged weights f32 -> bf16: one launch converts w1, w3, w2 (grid-stride, 8 elems/thread)
__global__ void wcvt_all_kernel(const float* __restrict__ w1, const float* __restrict__ w3,
                                const float* __restrict__ w2,
                                unsigned short* __restrict__ w1b, unsigned short* __restrict__ w3b,
                                unsigned short* __restrict__ w2b, int n8each) {
    int stride = gridDim.x * blockDim.x;
    int total = n8each * 3;
    for (int g = blockIdx.x * blockDim.x + threadIdx.x; g < total; g += stride) {
        int tsel = g / n8each;
        int i = g - tsel * n8each;
        const float* src = (tsel == 0) ? w1 : (tsel == 1) ? w3 : w2;
        unsigned short* dst = (tsel == 0) ? w1b : (tsel == 1) ? w3b : w2b;
        const float4* p = (const float4*)src + (size_t)i * 2;
        float4 a = p[0], b = p[1];
        uint4 o;
        o.x = (unsigned)f2bf(a.x) | ((unsigned)f2bf(a.y) << 16);
        o.y = (unsigned)f2bf(a.z) | ((unsigned)f2bf(a.w) << 16);
        o.z = (unsigned)f2bf(b.x) | ((unsigned)f2bf(b.y) << 16);
        o.w = (unsigned)f2bf(b.z) | ((unsigned)f2bf(b.w) << 16);
        *(uint4*)(dst + (size_t)i * 8) = o;
    }
}

// GEMM1 (flat over all experts): h = silu(Xg*W1e^T) * (Xg*W3e^T)
// T2 swizzle via rule 21: linear gload_lds dest + inverse-swizzled global SOURCE
// (sslot = (lane&7)^(lane>>3)) + XOR-swizzled ds_read addresses.
// launch_bounds (256,2): needs ~84 VGPR + 128 AGPR; (256,3) spills (R5).
__global__ __launch_bounds__(256, 2)
void gemm1_kernel(const unsigned short* __restrict__ xb,
                  const unsigned short* __restrict__ w1b, const unsigned short* __restrict__ w3b,
                  unsigned short* __restrict__ h_bf,
                  const int* __restrict__ frows, const int* __restrict__ tile_e,
                  const int* __restrict__ ntiles) {
    const int bt = blockIdx.y;
    if (bt >= ntiles[0]) return;
    __shared__ unsigned short aT[128 * 64];
    __shared__ unsigned short b1T[128 * 64];
    __shared__ unsigned short b3T[128 * 64];
    const int e = tile_e[bt];
    const int n0 = blockIdx.x * 128;
    const int tid = threadIdx.x, wave = tid >> 6, lane = tid & 63;
    const int wm = wave >> 1, wn = wave & 1;

    const int sslot = (lane & 7) ^ (lane >> 3);
    const unsigned short *aS[4], *b1S[4], *b3S[4];
    unsigned short *aD[4], *b1D[4], *b3D[4];
#pragma unroll
    for (int i = 0; i < 4; ++i) {
        int rowl = wave * 32 + i * 8 + (lane >> 3);
        int tok = frows[bt * 128 + rowl];
        int c8 = sslot * 8;
        aS[i]  = xb  + (size_t)tok * H_DIM + c8;
        b1S[i] = w1b + ((size_t)e * I_DIM + n0 + rowl) * H_DIM + c8;
        b3S[i] = w3b + ((size_t)e * I_DIM + n0 + rowl) * H_DIM + c8;
        int r0l = wave * 32 + i * 8;
        aD[i] = &aT[r0l * 64]; b1D[i] = &b1T[r0l * 64]; b3D[i] = &b3T[r0l * 64];
    }
    f32x4 acc1[4][4] = {};
    f32x4 acc3[4][4] = {};

    for (int kt = 0; kt < H_DIM / 64; ++kt) {
#pragma unroll
        for (int i = 0; i < 4; ++i) {
            gload16(aS[i], aD[i]);
            gload16(b1S[i], b1D[i]);
            gload16(b3S[i], b3D[i]);
            aS[i] += 64; b1S[i] += 64; b3S[i] += 64;
        }
        __syncthreads();
#pragma unroll
        for (int ks = 0; ks < 2; ++ks) {
            const int slot = ks * 4 + (lane >> 4);
            bf16x8 af[4], b1f[4], b3f[4];
#pragma unroll
            for (int m = 0; m < 4; ++m) {
                int row = wm * 64 + m * 16 + (lane & 15);
                af[m] = *(const bf16x8*)&aT[row * 64 + ((slot ^ (row & 7)) << 3)];
            }
#pragma unroll
            for (int n = 0; n < 4; ++n) {
                int row = wn * 64 + n * 16 + (lane & 15);
                int offr = row * 64 + ((slot ^ (row & 7)) << 3);
                b1f[n] = *(const bf16x8*)&b1T[offr];
                b3f[n] = *(const bf16x8*)&b3T[offr];
            }
#pragma unroll
            for (int m = 0; m < 4; ++m)
#pragma unroll
                for (int n = 0; n < 4; ++n) {
                    acc1[m][n] = __builtin_amdgcn_mfma_f32_16x16x32_bf16(af[m], b1f[n], acc1[m][n], 0, 0, 0);
                    acc3[m][n] = __builtin_amdgcn_mfma_f32_16x16x32_bf16(af[m], b3f[n], acc3[m][n], 0, 0, 0);
                }
        }
        __syncthreads();
    }
#pragma unroll
    for (int m = 0; m < 4; ++m)
#pragma unroll
        for (int r = 0; r < 4; ++r) {
            int rowl = wm * 64 + m * 16 + (lane >> 4) * 4 + r;
            size_t hoff = (size_t)(bt * 128 + rowl) * I_DIM;
#pragma unroll
            for (int n = 0; n < 4; ++n) {
                int col = n0 + wn * 64 + n * 16 + (lane & 15);
                float v1 = acc1[m][n][r], v3 = acc3[m][n][r];
                float hv = (v1 / (1.f + expf(-v1))) * v3;
                h_bf[hoff + col] = f2bf(hv);
            }
        }
}

// GEMM2 (flat): out[t,:] += combine[t,e] * (Hg * W2e^T); same swizzle scheme.
// atomicAdd writeback: exactly 2 contributions per element onto zeroed out;
// f32 add commutes => deterministic.
__global__ __launch_bounds__(256, 2)
void gemm2_kernel(const unsigned short* __restrict__ h_bf, const unsigned short* __restrict__ w2b,
                  const float* __restrict__ combine, float* __restrict__ out,
                  const int* __restrict__ frows, const int* __restrict__ tile_e,
                  const int* __restrict__ tile_valid, const int* __restrict__ ntiles) {
    const int bt = blockIdx.y;
    if (bt >= ntiles[0]) return;
    __shared__ unsigned short aT[128 * 64];
    __shared__ unsigned short bT[128 * 64];
    const int e = tile_e[bt];
    const int valid = tile_valid[bt];
    const int n0 = blockIdx.x * 128;
    const int tid = threadIdx.x, wave = tid >> 6, lane = tid & 63;
    const int wm = wave >> 1, wn = wave & 1;

    const int sslot = (lane & 7) ^ (lane >> 3);
    const unsigned short *aS[4], *bS[4];
    unsigned short *aD[4], *bD[4];
#pragma unroll
    for (int i = 0; i < 4; ++i) {
        int rowl = wave * 32 + i * 8 + (lane >> 3);
        int c8 = sslot * 8;
        aS[i] = h_bf + (size_t)(bt * 128 + rowl) * I_DIM + c8;
        bS[i] = w2b + ((size_t)e * H_DIM + n0 + rowl) * I_DIM + c8;
        int r0l = wave * 32 + i * 8;
        aD[i] = &aT[r0l * 64]; bD[i] = &bT[r0l * 64];
    }
    f32x4 acc[4][4] = {};

    for (int kt = 0; kt < I_DIM / 64; ++kt) {
#pragma unroll
        for (int i = 0; i < 4; ++i) {
            gload16(aS[i], aD[i]);
            gload16(bS[i], bD[i]);
            aS[i] += 64; bS[i] += 64;
        }
        __syncthreads();
#pragma unroll
        for (int ks = 0; ks < 2; ++ks) {
            const int slot = ks * 4 + (lane >> 4);
            bf16x8 af[4], bfr[4];
#pragma unroll
            for (int m = 0; m < 4; ++m) {
                int row = wm * 64 + m * 16 + (lane & 15);
                af[m] = *(const bf16x8*)&aT[row * 64 + ((slot ^ (row & 7)) << 3)];
            }
#pragma unroll
            for (int n = 0; n < 4; ++n) {
                int row = wn * 64 + n * 16 + (lane & 15);
                bfr[n] = *(const bf16x8*)&bT[row * 64 + ((slot ^ (row & 7)) << 3)];
            }
#pragma unroll
            for (int m = 0; m < 4; ++m)
#pragma unroll
                for (int n = 0; n < 4; ++n)
                    acc[m][n] = __builtin_amdgcn_mfma_f32_16x16x32_bf16(af[m], bfr[n], acc[m][n], 0, 0, 0);
        }
        __syncthreads();
    }
#pragma unroll
    for (int m = 0; m < 4; ++m)
#pragma unroll
        for (int r = 0; r < 4; ++r) {
            int rowl = wm * 64 + m * 16 + (lane >> 4) * 4 + r;
            if (rowl < valid) {
                int t = frows[bt * 128 + rowl];
                float cmb = combine[(size_t)t * NEXP + e];
#pragma unroll
                for (int n = 0; n < 4; ++n) {
                    int col = n0 + wn * 64 + n * 16 + (lane & 15);
                    atomicAdd(&out[(size_t)t * H_DIM + col], cmb * acc[m][n][r]);
                }
            }
        }
}

// ================= fallback path (R1, verified) =================

__global__ void cvt_x_fb(const float* __restrict__ x, unsigned short* __restrict__ xb) {
    size_t i = (size_t)blockIdx.x * blockDim.x + threadIdx.x;
    const float4* p = (const float4*)x + i * 2;
    float4 a = p[0], b = p[1];
    uint4 o;
    o.x = (unsigned)f2bf(a.x) | ((unsigned)f2bf(a.y) << 16);
    o.y = (unsigned)f2bf(a.z) | ((unsigned)f2bf(a.w) << 16);
    o.z = (unsigned)f2bf(b.x) | ((unsigned)f2bf(b.y) << 16);
    o.w = (unsigned)f2bf(b.z) | ((unsigned)f2bf(b.w) << 16);
    *(uint4*)(xb + i * 8) = o;
}

__global__ void router_fb(const float* __restrict__ x, const float* __restrict__ gw,
                          const float* __restrict__ gb, float* __restrict__ combine,
                          int* __restrict__ rowlist, int* __restrict__ count) {
    int wave = threadIdx.x >> 6, lane = threadIdx.x & 63;
    int t = blockIdx.x * 4 + wave;
    float acc[NEXP];
#pragma unroll
    for (int e = 0; e < NEXP; ++e) acc[e] = 0.f;
    const float4* xr = (const float4*)(x + (size_t)t * H_DIM);
#pragma unroll
    for (int j = 0; j < 4; ++j) {
        int c = j * 64 + lane;
        float4 xv = xr[c];
#pragma unroll
        for (int e = 0; e < NEXP; ++e) {
            float4 gv = ((const float4*)(gw + (size_t)e * H_DIM))[c];
            acc[e] += xv.x * gv.x + xv.y * gv.y + xv.z * gv.z + xv.w * gv.w;
        }
    }
#pragma unroll
    for (int off = 32; off; off >>= 1)
#pragma unroll
        for (int e = 0; e < NEXP; ++e) acc[e] += __shfl_xor(acc[e], off, 64);
    if (lane == 0) {
        float logit[NEXP], mx = -1e30f;
#pragma unroll
        for (int e = 0; e < NEXP; ++e) { logit[e] = acc[e] + gb[e]; mx = fmaxf(mx, logit[e]); }
        float p[NEXP], s = 0.f;
#pragma unroll
        for (int e = 0; e < NEXP; ++e) { p[e] = expf(logit[e] - mx); s += p[e]; }
        float inv = 1.f / s;
#pragma unroll
        for (int e = 0; e < NEXP; ++e) p[e] *= inv;
        int i1 = 0;
#pragma unroll
        for (int e = 1; e < NEXP; ++e) if (p[e] > p[i1]) i1 = e;
        int i2 = -1;
#pragma unroll
        for (int e = 0; e < NEXP; ++e) if (e != i1 && (i2 < 0 || p[e] > p[i2])) i2 = e;
#pragma unroll
        for (int e = 0; e < NEXP; ++e)
            combine[(size_t)t * NEXP + e] = (e == i1 || e == i2) ? p[e] : 0.f;
        int pos1 = atomicAdd(&count[i1], 1); rowlist[i1 * T_TOK + pos1] = t;
        int pos2 = atomicAdd(&count[i2], 1); rowlist[i2 * T_TOK + pos2] = t;
    }
}

__global__ __launch_bounds__(256, 2)
void gemm1_fb(const unsigned short* __restrict__ x_bf,
              const float* __restrict__ w1, const float* __restrict__ w3,
              unsigned short* __restrict__ h_bf,
              const int* __restrict__ rowlist, const int* __restrict__ count, int e) {
    __shared__ unsigned short aT[128 * 64];
    __shared__ unsigned short b1T[128 * 64];
    __shared__ unsigned short b3T[128 * 64];
    __shared__ int rl[128];
    const int cnt = count[e];
    const int r0 = blockIdx.y * 128;
    if (r0 >= cnt) return;
    const int n0 = blockIdx.x * 128;
    const float* __restrict__ w1e = w1 + (size_t)e * I_DIM * H_DIM;
    const float* __restrict__ w3e = w3 + (size_t)e * I_DIM * H_DIM;
    const int tid = threadIdx.x;
    if (tid < 128) {
        int r = r0 + tid;
        rl[tid] = rowlist[e * T_TOK + (r < cnt ? r : 0)];
    }
    __syncthreads();
    const int wave = tid >> 6, lane = tid & 63;
    const int wm = wave >> 1, wn = wave & 1;
    f32x4 acc1[4][4] = {};
    f32x4 acc3[4][4] = {};

    for (int kt = 0; kt < H_DIM / 64; ++kt) {
        const int k0 = kt * 64;
#pragma unroll
        for (int it = 0; it < 4; ++it) {
            int c = it * 256 + tid, row = c >> 3, slot = c & 7;
            uint4 v = *(const uint4*)(x_bf + (size_t)rl[row] * H_DIM + k0 + slot * 8);
            *(uint4*)&aT[row * 64 + ((slot ^ (row & 7)) << 3)] = v;
        }
#pragma unroll
        for (int it = 0; it < 8; ++it) {
            int c = it * 256 + tid, row = c >> 4, cw = c & 15;
            size_t goff = (size_t)(n0 + row) * H_DIM + k0 + cw * 4;
            float4 v1 = *(const float4*)(w1e + goff);
            float4 v3 = *(const float4*)(w3e + goff);
            int offr = row * 64 + (((cw >> 1) ^ (row & 7)) << 3) + (cw & 1) * 4;
            ushort4 p1 = { f2bf(v1.x), f2bf(v1.y), f2bf(v1.z), f2bf(v1.w) };
            ushort4 p3 = { f2bf(v3.x), f2bf(v3.y), f2bf(v3.z), f2bf(v3.w) };
            *(ushort4*)&b1T[offr] = p1;
            *(ushort4*)&b3T[offr] = p3;
        }
        __syncthreads();
#pragma unroll
        for (int ks = 0; ks < 2; ++ks) {
            const int slot = ks * 4 + (lane >> 4);
            bf16x8 af[4], b1f[4], b3f[4];
#pragma unroll
            for (int m = 0; m < 4; ++m) {
                int row = wm * 64 + m * 16 + (lane & 15);
                af[m] = *(const bf16x8*)&aT[row * 64 + ((slot ^ (row & 7)) << 3)];
            }
#pragma unroll
            for (int n = 0; n < 4; ++n) {
                int row = wn * 64 + n * 16 + (lane & 15);
                int offr = row * 64 + ((slot ^ (row & 7)) << 3);
                b1f[n] = *(const bf16x8*)&b1T[offr];
                b3f[n] = *(const bf16x8*)&b3T[offr];
            }
#pragma unroll
            for (int m = 0; m < 4; ++m)
#pragma unroll
                for (int n = 0; n < 4; ++n) {
                    acc1[m][n] = __builtin_amdgcn_mfma_f32_16x16x32_bf16(af[m], b1f[n], acc1[m][n], 0, 0, 0);
                    acc3[m][n] = __builtin_amdgcn_mfma_f32_16x16x32_bf16(af[m], b3f[n], acc3[m][n], 0, 0, 0);
                }
        }
        __syncthreads();
    }
#pragma unroll
    for (int m = 0; m < 4; ++m)
#pragma unroll
        for (int r = 0; r < 4; ++r) {
            int rowl = wm * 64 + m * 16 + (lane >> 4) * 4 + r;
            int ridx = r0 + rowl;
            if (ridx < cnt) {
#pragma unroll
                for (int n = 0; n < 4; ++n) {
                    int col = n0 + wn * 64 + n * 16 + (lane & 15);
                    float v1 = acc1[m][n][r], v3 = acc3[m][n][r];
                    float hv = (v1 / (1.f + expf(-v1))) * v3;
                    h_bf[(size_t)ridx * I_DIM + col] = f2bf(hv);
                }
            }
        }
}

__global__ __launch_bounds__(256, 2)
void gemm2_fb(const unsigned short* __restrict__ h_bf, const float* __restrict__ w2,
              const float* __restrict__ combine, float* __restrict__ out,
              const int* __restrict__ rowlist, const int* __restrict__ count, int e) {
    __shared__ unsigned short aT[128 * 64];
    __shared__ unsigned short bT[128 * 64];
    __shared__ int rl[128];
    const int cnt = count[e];
    const int r0 = blockIdx.y * 128;
    if (r0 >= cnt) return;
    const int n0 = blockIdx.x * 128;
    const float* __restrict__ w2e = w2 + (size_t)e * H_DIM * I_DIM;
    const int tid = threadIdx.x;
    if (tid < 128) {
        int r = r0 + tid;
        rl[tid] = rowlist[e * T_TOK + (r < cnt ? r : 0)];
    }
    __syncthreads();
    const int wave = tid >> 6, lane = tid & 63;
    const int wm = wave >> 1, wn = wave & 1;
    f32x4 acc[4][4] = {};

    for (int kt = 0; kt < I_DIM / 64; ++kt) {
        const int k0 = kt * 64;
#pragma unroll
        for (int it = 0; it < 4; ++it) {
            int c = it * 256 + tid, row = c >> 3, slot = c & 7;
            uint4 v = *(const uint4*)(h_bf + (size_t)(r0 + row) * I_DIM + k0 + slot * 8);
            *(uint4*)&aT[row * 64 + ((slot ^ (row & 7)) << 3)] = v;
        }
#pragma unroll
        for (int it = 0; it < 8; ++it) {
            int c = it * 256 + tid, row = c >> 4, cw = c & 15;
            float4 v = *(const float4*)(w2e + (size_t)(n0 + row) * I_DIM + k0 + cw * 4);
            int offr = row * 64 + (((cw >> 1) ^ (row & 7)) << 3) + (cw & 1) * 4;
            ushort4 p = { f2bf(v.x), f2bf(v.y), f2bf(v.z), f2bf(v.w) };
            *(ushort4*)&bT[offr] = p;
        }
        __syncthreads();
#pragma unroll
        for (int ks = 0; ks < 2; ++ks) {
            const int slot = ks * 4 + (lane >> 4);
            bf16x8 af[4], bfr[4];
#pragma unroll
            for (int m = 0; m < 4; ++m) {
                int row = wm * 64 + m * 16 + (lane & 15);
                af[m] = *(const bf16x8*)&aT[row * 64 + ((slot ^ (row & 7)) << 3)];
            }
#pragma unroll
            for (int n = 0; n < 4; ++n) {
                int row = wn * 64 + n * 16 + (lane & 15);
                bfr[n] = *(const bf16x8*)&bT[row * 64 + ((slot ^ (row & 7)) << 3)];
            }
#pragma unroll
            for (int m = 0; m < 4; ++m)
#pragma unroll
                for (int n = 0; n < 4; ++n)
                    acc[m][n] = __builtin_amdgcn_mfma_f32_16x16x32_bf16(af[m], bfr[n], acc[m][n], 0, 0, 0);
        }
        __syncthreads();
    }
#pragma unroll
    for (int m = 0; m < 4; ++m)
#pragma unroll
        for (int r = 0; r < 4; ++r) {
            int rowl = wm * 64 + m * 16 + (lane >> 4) * 4 + r;
            int ridx = r0 + rowl;
            if (ridx < cnt) {
                int t = rl[rowl];
                float cmb = combine[(size_t)t * NEXP + e];
#pragma unroll
                for (int n = 0; n < 4; ++n) {
                    int col = n0 + wn * 64 + n * 16 + (lane & 15);
                    out[(size_t)t * H_DIM + col] += cmb * acc[m][n][r];
                }
            }
        }
}

// ================= launch =================

extern "C" void kernel_launch(void* const* d_in, const int* in_sizes, int n_in,
                              void* d_out, int out_size, void* d_ws, size_t ws_size,
                              hipStream_t stream) {
    const float* x  = (const float*)d_in[0];
    const float* gw = (const float*)d_in[1];
    const float* gb = (const float*)d_in[2];
    const float* w1 = (const float*)d_in[3];
    const float* w2 = (const float*)d_in[4];
    const float* w3 = (const float*)d_in[5];
    float* out = (float*)d_out;
    char* ws = (char*)d_ws;

    const size_t WELEMS = (size_t)NEXP * I_DIM * H_DIM;      // 29,360,128
    // fast-path layout
    size_t off = 0;
    unsigned short* xb  = (unsigned short*)(ws + off); off += (size_t)T_TOK * H_DIM * 2;       // 16 MB
    unsigned short* w1b = (unsigned short*)(ws + off); off += WELEMS * 2;                      // 56 MB
    unsigned short* w3b = (unsigned short*)(ws + off); off += WELEMS * 2;
    unsigned short* w2b = (unsigned short*)(ws + off); off += WELEMS * 2;
    unsigned short* hb  = (unsigned short*)(ws + off); off += (size_t)MAX_TILES * 128 * I_DIM * 2; // 119 MB
    float* combine      = (float*)(ws + off);          off += (size_t)T_TOK * NEXP * 4;
    int* pair           = (int*)(ws + off);            off += (size_t)T_TOK * 4;
    int* frows          = (int*)(ws + off);            off += (size_t)MAX_TILES * 128 * 4;
    int* tile_e         = (int*)(ws + off);            off += 1024;
    int* tile_valid     = (int*)(ws + off);            off += 1024;
    int* ntiles         = (int*)(ws + off);            off += 1024;
    const size_t WS_NEEDED = off;

    (void)hipMemsetAsync(out, 0, (size_t)T_TOK * H_DIM * sizeof(float), stream);

    if (ws_size >= WS_NEEDED) {
        const int n8 = (int)(WELEMS / 8);
        wcvt_all_kernel<<<dim3(4096), dim3(256), 0, stream>>>(w1, w3, w2, w1b, w3b, w2b, n8);
        router_kernel<<<dim3(T_TOK / 4), dim3(256), 0, stream>>>(x, gw, gb, xb, combine, pair);
        build_lists_kernel<<<dim3(NEXP), dim3(1024), 0, stream>>>(pair, frows, tile_e, tile_valid, ntiles);
        gemm1_kernel<<<dim3(I_DIM / 128, MAX_TILES), dim3(256), 0, stream>>>(
            xb, w1b, w3b, hb, frows, tile_e, ntiles);
        gemm2_kernel<<<dim3(H_DIM / 128, MAX_TILES), dim3(256), 0, stream>>>(
            hb, w2b, combine, out, frows, tile_e, tile_valid, ntiles);
    } else {
        // fallback: R1 layout (76 MB)
        unsigned short* x_bf    = (unsigned short*)ws;
        unsigned short* h_bf    = (unsigned short*)(ws + 16777216);
        float*          fcomb   = (float*)(ws + 16777216 + 58720256);
        int*            rowlist = (int*)(ws + 16777216 + 58720256 + 262144);
        int*            count   = (int*)(ws + 16777216 + 58720256 + 262144 + 262144);

        (void)hipMemsetAsync(count, 0, NEXP * sizeof(int), stream);
        cvt_x_fb<<<dim3(T_TOK * H_DIM / (256 * 8)), dim3(256), 0, stream>>>(x, x_bf);
        router_fb<<<dim3(T_TOK / 4), dim3(256), 0, stream>>>(x, gw, gb, fcomb, rowlist, count);
        for (int e = 0; e < NEXP; ++e) {
            gemm1_fb<<<dim3(I_DIM / 128, T_TOK / 128), dim3(256), 0, stream>>>(
                x_bf, w1, w3, h_bf, rowlist, count, e);
            gemm2_fb<<<dim3(H_DIM / 128, T_TOK / 128), dim3(256), 0, stream>>>(
                h_bf, w2, fcomb, out, rowlist, count, e);
        }
    }
}

// Round 12
// 595.639 us; speedup vs baseline: 1.0760x; 1.0118x over previous
//
#include <hip/hip_runtime.h>

#define T_TOK 8192
#define H_DIM 1024
#define I_DIM 3584
#define NEXP 8
#define MAX_TILES 136          // sum ceil(cnt_e/128) <= 128 + 7, padded

typedef __attribute__((ext_vector_type(4))) float f32x4;
typedef __attribute__((ext_vector_type(8))) short bf16x8;

__device__ __forceinline__ unsigned short f2bf(float f) {
    union { float f; unsigned u; } v; v.f = f;
    unsigned r = v.u + 0x7FFFu + ((v.u >> 16) & 1u);
    return (unsigned short)(r >> 16);
}

__device__ __forceinline__ void gload16(const unsigned short* g, unsigned short* l) {
    __builtin_amdgcn_global_load_lds(
        (const __attribute__((address_space(1))) void*)g,
        (__attribute__((address_space(3))) void*)l, 16, 0, 0);
}

// ================= fast path =================

// router: logits -> softmax -> top2; emits pair[t], combine[t][8], and xb (bf16 x)
__global__ void router_kernel(const float* __restrict__ x, const float* __restrict__ gw,
                              const float* __restrict__ gb, unsigned short* __restrict__ xb,
                              float* __restrict__ combine, int* __restrict__ pair) {
    int wave = threadIdx.x >> 6, lane = threadIdx.x & 63;
    int t = blockIdx.x * 4 + wave;
    float acc[NEXP];
#pragma unroll
    for (int e = 0; e < NEXP; ++e) acc[e] = 0.f;
    const float4* xr = (const float4*)(x + (size_t)t * H_DIM);
#pragma unroll
    for (int j = 0; j < 4; ++j) {
        int c = j * 64 + lane;
        float4 xv = xr[c];
        ushort4 o = { f2bf(xv.x), f2bf(xv.y), f2bf(xv.z), f2bf(xv.w) };
        *(ushort4*)(xb + (size_t)t * H_DIM + c * 4) = o;
#pragma unroll
        for (int e = 0; e < NEXP; ++e) {
            float4 gv = ((const float4*)(gw + (size_t)e * H_DIM))[c];
            acc[e] += xv.x * gv.x + xv.y * gv.y + xv.z * gv.z + xv.w * gv.w;
        }
    }
#pragma unroll
    for (int off = 32; off; off >>= 1)
#pragma unroll
        for (int e = 0; e < NEXP; ++e) acc[e] += __shfl_xor(acc[e], off, 64);
    if (lane == 0) {
        float logit[NEXP], mx = -1e30f;
#pragma unroll
        for (int e = 0; e < NEXP; ++e) { logit[e] = acc[e] + gb[e]; mx = fmaxf(mx, logit[e]); }
        float p[NEXP], s = 0.f;
#pragma unroll
        for (int e = 0; e < NEXP; ++e) { p[e] = expf(logit[e] - mx); s += p[e]; }
        float inv = 1.f / s;
#pragma unroll
        for (int e = 0; e < NEXP; ++e) p[e] *= inv;
        int i1 = 0;
#pragma unroll
        for (int e = 1; e < NEXP; ++e) if (p[e] > p[i1]) i1 = e;
        int i2 = -1;
#pragma unroll
        for (int e = 0; e < NEXP; ++e) if (e != i1 && (i2 < 0 || p[e] > p[i2])) i2 = e;
        float4 c0, c1;
        c0.x = (0 == i1 || 0 == i2) ? p[0] : 0.f;  c0.y = (1 == i1 || 1 == i2) ? p[1] : 0.f;
        c0.z = (2 == i1 || 2 == i2) ? p[2] : 0.f;  c0.w = (3 == i1 || 3 == i2) ? p[3] : 0.f;
        c1.x = (4 == i1 || 4 == i2) ? p[4] : 0.f;  c1.y = (5 == i1 || 5 == i2) ? p[5] : 0.f;
        c1.z = (6 == i1 || 6 == i2) ? p[6] : 0.f;  c1.w = (7 == i1 || 7 == i2) ? p[7] : 0.f;
        *(float4*)(combine + (size_t)t * NEXP) = c0;
        *(float4*)(combine + (size_t)t * NEXP + 4) = c1;
        pair[t] = i1 | (i2 << 8);
    }
}

// deterministic, atomic-free list builder: 8 blocks (one per expert), 1024 threads.
__global__ void build_lists_kernel(const int* __restrict__ pair, int* __restrict__ frows,
                                   int* __restrict__ tile_e, int* __restrict__ tile_valid,
                                   int* __restrict__ ntiles) {
    const int e = blockIdx.x;
    const int tid = threadIdx.x;
    const int wave = tid >> 6, lane = tid & 63;
    __shared__ int wtot[16][NEXP];
    __shared__ int stot[NEXP];
    __shared__ int wcnt[16];

    int myp[8];
    int tcnt[NEXP] = {0, 0, 0, 0, 0, 0, 0, 0};
#pragma unroll
    for (int c = 0; c < 8; ++c) {
        int pr = pair[c * 1024 + tid];
        myp[c] = pr;
        int e1 = pr & 255, e2 = (pr >> 8) & 255;
#pragma unroll
        for (int j = 0; j < NEXP; ++j) {
            unsigned long long m = __ballot(e1 == j || e2 == j);
            if (lane == 0) tcnt[j] += (int)__popcll(m);
        }
    }
    if (lane == 0) {
#pragma unroll
        for (int j = 0; j < NEXP; ++j) wtot[wave][j] = tcnt[j];
    }
    __syncthreads();
    if (tid < NEXP) {
        int s = 0;
        for (int w = 0; w < 16; ++w) s += wtot[w][tid];
        stot[tid] = s;
    }
    __syncthreads();

    int gbase = 0, tbase = 0, totTiles = 0;
#pragma unroll
    for (int j = 0; j < NEXP; ++j) {
        int tj = (stot[j] + 127) >> 7;
        if (j < e) { gbase += tj << 7; tbase += tj; }
        totTiles += tj;
    }
    const int cnt = stot[e];
    const int mytiles = (cnt + 127) >> 7;

    int base = gbase;
    for (int c = 0; c < 8; ++c) {
        int pr = myp[c];
        bool pred = ((pr & 255) == e) || (((pr >> 8) & 255) == e);
        unsigned long long m = __ballot(pred);
        if (lane == 0) wcnt[wave] = (int)__popcll(m);
        __syncthreads();
        int wb = 0;
        for (int w = 0; w < wave; ++w) wb += wcnt[w];
        int ctot = 0;
        for (int w = 0; w < 16; ++w) ctot += wcnt[w];
        if (pred) {
            int wp = (int)__popcll(m & ((1ull << lane) - 1ull));
            frows[base + wb + wp] = c * 1024 + tid;
        }
        base += ctot;
        __syncthreads();
    }
    if (cnt > 0) {
        int first = frows[gbase];
        for (int p = cnt + tid; p < (mytiles << 7); p += 1024) frows[gbase + p] = first;
        if (tid < mytiles) {
            tile_e[tbase + tid] = e;
            int v = cnt - (tid << 7);
            tile_valid[tbase + tid] = v > 128 ? 128 : v;
        }
    }
    if (e == 0 && tid == 0) ntiles[0] = totTiles;
}

// weights f32 -> bf16 (grid-stride, 8 elems/thread)
__global__ void wcvt_kernel(const float* __restrict__ src, unsigned short* __restrict__ dst, int n8) {
    int stride = gridDim.x * blockDim.x;
    for (int i = blockIdx.x * blockDim.x + threadIdx.x; i < n8; i += stride) {
        const float4* p = (const float4*)src + (size_t)i * 2;
        float4 a = p[0], b = p[1];
        uint4 o;
        o.x = (unsigned)f2bf(a.x) | ((unsigned)f2bf(a.y) << 16);
        o.y = (unsigned)f2bf(a.z) | ((unsigned)f2bf(a.w) << 16);
        o.z = (unsigned)f2bf(b.x) | ((unsigned)f2bf(b.y) << 16);
        o.w = (unsigned)f2bf(b.z) | ((unsigned)f2bf(b.w) << 16);
        *(uint4*)(dst + (size_t)i * 8) = o;
    }
}

// w1,w3 f32 -> interleaved bf16 w13i[e][7168][1024] (R7/R8-verified):
// row r: s=r&31, rg=r>>5; s<16 -> w1 row rg*16+s ; s>=16 -> w3 row rg*16+s-16
__global__ void wcvt13_kernel(const float* __restrict__ w1, const float* __restrict__ w3,
                              unsigned short* __restrict__ dst, int n8) {
    int stride = gridDim.x * blockDim.x;
    for (int g = blockIdx.x * blockDim.x + threadIdx.x; g < n8; g += stride) {
        int col = (g & 127) * 8;
        int er = g >> 7;
        int r = er % 7168;
        int e = er / 7168;
        int s = r & 31, rg = r >> 5;
        const float* src = (s < 16)
            ? (w1 + ((size_t)e * I_DIM + rg * 16 + s) * H_DIM + col)
            : (w3 + ((size_t)e * I_DIM + rg * 16 + (s - 16)) * H_DIM + col);
        float4 a = *(const float4*)src;
        float4 b = *(const float4*)(src + 4);
        uint4 o;
        o.x = (unsigned)f2bf(a.x) | ((unsigned)f2bf(a.y) << 16);
        o.y = (unsigned)f2bf(a.z) | ((unsigned)f2bf(a.w) << 16);
        o.z = (unsigned)f2bf(b.x) | ((unsigned)f2bf(b.y) << 16);
        o.w = (unsigned)f2bf(b.z) | ((unsigned)f2bf(b.w) << 16);
        *(uint4*)(dst + (size_t)g * 8) = o;
    }
}

// GEMM1 (single-B via interleaved w13i): h = silu(Xg*W1e^T) * (Xg*W3e^T)
// 128x128 tile: A = 128 gathered x rows, B = 128 interleaved w13 rows (= 64 I-cols).
// LDS 32KB (2 tiles), acc 4x4 single (64 AGPR) + ~84 VGPR = ~148 unified -> fits
// launch_bounds(256,3): 3 blocks/CU, 12 waves/CU (vs R11's 2 blocks at 48KB/128AGPR).
// T2 swizzle via rule 21 (pre-swizzled source + XOR'd ds_read), R6-verified.
__global__ __launch_bounds__(256, 3)
void gemm1_kernel(const unsigned short* __restrict__ xb,
                  const unsigned short* __restrict__ w13b,
                  unsigned short* __restrict__ h_bf,
                  const int* __restrict__ frows, const int* __restrict__ tile_e,
                  const int* __restrict__ ntiles) {
    const int bt = blockIdx.y;
    if (bt >= ntiles[0]) return;
    __shared__ unsigned short aT[128 * 64];
    __shared__ unsigned short bT[128 * 64];
    const int e = tile_e[bt];
    const int n0w = blockIdx.x * 128;          // interleaved-row base
    const int tid = threadIdx.x, wave = tid >> 6, lane = tid & 63;
    const int wm = wave >> 1, wn = wave & 1;

    const int sslot = (lane & 7) ^ (lane >> 3);
    const unsigned short *aS[4], *bS[4];
    unsigned short *aD[4], *bD[4];
#pragma unroll
    for (int i = 0; i < 4; ++i) {
        int rowl = wave * 32 + i * 8 + (lane >> 3);
        int tok = frows[bt * 128 + rowl];
        int c8 = sslot * 8;
        aS[i] = xb   + (size_t)tok * H_DIM + c8;
        bS[i] = w13b + ((size_t)e * 7168 + n0w + rowl) * H_DIM + c8;
        int r0l = wave * 32 + i * 8;
        aD[i] = &aT[r0l * 64]; bD[i] = &bT[r0l * 64];
    }
    f32x4 acc[4][4] = {};

    for (int kt = 0; kt < H_DIM / 64; ++kt) {
#pragma unroll
        for (int i = 0; i < 4; ++i) {
            gload16(aS[i], aD[i]);
            gload16(bS[i], bD[i]);
            aS[i] += 64; bS[i] += 64;
        }
        __syncthreads();
#pragma unroll
        for (int ks = 0; ks < 2; ++ks) {
            const int slot = ks * 4 + (lane >> 4);
            bf16x8 af[4], bfr[4];
#pragma unroll
            for (int m = 0; m < 4; ++m) {
                int row = wm * 64 + m * 16 + (lane & 15);
                af[m] = *(const bf16x8*)&aT[row * 64 + ((slot ^ (row & 7)) << 3)];
            }
#pragma unroll
            for (int n = 0; n < 4; ++n) {
                int row = wn * 64 + n * 16 + (lane & 15);
                bfr[n] = *(const bf16x8*)&bT[row * 64 + ((slot ^ (row & 7)) << 3)];
            }
#pragma unroll
            for (int m = 0; m < 4; ++m)
#pragma unroll
                for (int n = 0; n < 4; ++n)
                    acc[m][n] = __builtin_amdgcn_mfma_f32_16x16x32_bf16(af[m], bfr[n], acc[m][n], 0, 0, 0);
        }
        __syncthreads();
    }
    // epilogue: interleave means n=2u is a w1 16-row group, n=2u+1 the matching w3
    // group (same rg, same lane col). I-col = (blockIdx.x*4 + wn*2 + u)*16 + (lane&15).
#pragma unroll
    for (int m = 0; m < 4; ++m)
#pragma unroll
        for (int r = 0; r < 4; ++r) {
            int rowl = wm * 64 + m * 16 + (lane >> 4) * 4 + r;
            size_t hoff = (size_t)(bt * 128 + rowl) * I_DIM;
#pragma unroll
            for (int u = 0; u < 2; ++u) {
                int icol = blockIdx.x * 64 + wn * 32 + u * 16 + (lane & 15);
                float v1 = acc[m][2 * u][r], v3 = acc[m][2 * u + 1][r];
                float hv = (v1 / (1.f + expf(-v1))) * v3;
                h_bf[hoff + icol] = f2bf(hv);
            }
        }
}

// GEMM2 (flat, R6/R11-verified): out[t,:] += combine[t,e] * (Hg * W2e^T)
// atomicAdd writeback: exactly 2 contributions per element onto zeroed out;
// f32 add commutes => deterministic.
__global__ __launch_bounds__(256, 2)
void gemm2_kernel(const unsigned short* __restrict__ h_bf, const unsigned short* __restrict__ w2b,
                  const float* __restrict__ combine, float* __restrict__ out,
                  const int* __restrict__ frows, const int* __restrict__ tile_e,
                  const int* __restrict__ tile_valid, const int* __restrict__ ntiles) {
    const int bt = blockIdx.y;
    if (bt >= ntiles[0]) return;
    __shared__ unsigned short aT[128 * 64];
    __shared__ unsigned short bT[128 * 64];
    const int e = tile_e[bt];
    const int valid = tile_valid[bt];
    const int n0 = blockIdx.x * 128;
    const int tid = threadIdx.x, wave = tid >> 6, lane = tid & 63;
    const int wm = wave >> 1, wn = wave & 1;

    const int sslot = (lane & 7) ^ (lane >> 3);
    const unsigned short *aS[4], *bS[4];
    unsigned short *aD[4], *bD[4];
#pragma unroll
    for (int i = 0; i < 4; ++i) {
        int rowl = wave * 32 + i * 8 + (lane >> 3);
        int c8 = sslot * 8;
        aS[i] = h_bf + (size_t)(bt * 128 + rowl) * I_DIM + c8;
        bS[i] = w2b + ((size_t)e * H_DIM + n0 + rowl) * I_DIM + c8;
        int r0l = wave * 32 + i * 8;
        aD[i] = &aT[r0l * 64]; bD[i] = &bT[r0l * 64];
    }
    f32x4 acc[4][4] = {};

    for (int kt = 0; kt < I_DIM / 64; ++kt) {
#pragma unroll
        for (int i = 0; i < 4; ++i) {
            gload16(aS[i], aD[i]);
            gload16(bS[i], bD[i]);
            aS[i] += 64; bS[i] += 64;
        }
        __syncthreads();
#pragma unroll
        for (int ks = 0; ks < 2; ++ks) {
            const int slot = ks * 4 + (lane >> 4);
            bf16x8 af[4], bfr[4];
#pragma unroll
            for (int m = 0; m < 4; ++m) {
                int row = wm * 64 + m * 16 + (lane & 15);
                af[m] = *(const bf16x8*)&aT[row * 64 + ((slot ^ (row & 7)) << 3)];
            }
#pragma unroll
            for (int n = 0; n < 4; ++n) {
                int row = wn * 64 + n * 16 + (lane & 15);
                bfr[n] = *(const bf16x8*)&bT[row * 64 + ((slot ^ (row & 7)) << 3)];
            }
#pragma unroll
            for (int m = 0; m < 4; ++m)
#pragma unroll
                for (int n = 0; n < 4; ++n)
                    acc[m][n] = __builtin_amdgcn_mfma_f32_16x16x32_bf16(af[m], bfr[n], acc[m][n], 0, 0, 0);
        }
        __syncthreads();
    }
#pragma unroll
    for (int m = 0; m < 4; ++m)
#pragma unroll
        for (int r = 0; r < 4; ++r) {
            int rowl = wm * 64 + m * 16 + (lane >> 4) * 4 + r;
            if (rowl < valid) {
                int t = frows[bt * 128 + rowl];
                float cmb = combine[(size_t)t * NEXP + e];
#pragma unroll
                for (int n = 0; n < 4; ++n) {
                    int col = n0 + wn * 64 + n * 16 + (lane & 15);
                    atomicAdd(&out[(size_t)t * H_DIM + col], cmb * acc[m][n][r]);
                }
            }
        }
}

// ================= fallback path (R1, verified) =================

__global__ void cvt_x_fb(const float* __restrict__ x, unsigned short* __restrict__ xb) {
    size_t i = (size_t)blockIdx.x * blockDim.x + threadIdx.x;
    const float4* p = (const float4*)x + i * 2;
    float4 a = p[0], b = p[1];
    uint4 o;
    o.x = (unsigned)f2bf(a.x) | ((unsigned)f2bf(a.y) << 16);
    o.y = (unsigned)f2bf(a.z) | ((unsigned)f2bf(a.w) << 16);
    o.z = (unsigned)f2bf(b.x) | ((unsigned)f2bf(b.y) << 16);
    o.w = (unsigned)f2bf(b.z) | ((unsigned)f2bf(b.w) << 16);
    *(uint4*)(xb + i * 8) = o;
}

__global__ void router_fb(const float* __restrict__ x, const float* __restrict__ gw,
                          const float* __restrict__ gb, float* __restrict__ combine,
                          int* __restrict__ rowlist, int* __restrict__ count) {
    int wave = threadIdx.x >> 6, lane = threadIdx.x & 63;
    int t = blockIdx.x * 4 + wave;
    float acc[NEXP];
#pragma unroll
    for (int e = 0; e < NEXP; ++e) acc[e] = 0.f;
    const float4* xr = (const float4*)(x + (size_t)t * H_DIM);
#pragma unroll
    for (int j = 0; j < 4; ++j) {
        int c = j * 64 + lane;
        float4 xv = xr[c];
#pragma unroll
        for (int e = 0; e < NEXP; ++e) {
            float4 gv = ((const float4*)(gw + (size_t)e * H_DIM))[c];
            acc[e] += xv.x * gv.x + xv.y * gv.y + xv.z * gv.z + xv.w * gv.w;
        }
    }
#pragma unroll
    for (int off = 32; off; off >>= 1)
#pragma unroll
        for (int e = 0; e < NEXP; ++e) acc[e] += __shfl_xor(acc[e], off, 64);
    if (lane == 0) {
        float logit[NEXP], mx = -1e30f;
#pragma unroll
        for (int e = 0; e < NEXP; ++e) { logit[e] = acc[e] + gb[e]; mx = fmaxf(mx, logit[e]); }
        float p[NEXP], s = 0.f;
#pragma unroll
        for (int e = 0; e < NEXP; ++e) { p[e] = expf(logit[e] - mx); s += p[e]; }
        float inv = 1.f / s;
#pragma unroll
        for (int e = 0; e < NEXP; ++e) p[e] *= inv;
        int i1 = 0;
#pragma unroll
        for (int e = 1; e < NEXP; ++e) if (p[e] > p[i1]) i1 = e;
        int i2 = -1;
#pragma unroll
        for (int e = 0; e < NEXP; ++e) if (e != i1 && (i2 < 0 || p[e] > p[i2])) i2 = e;
#pragma unroll
        for (int e = 0; e < NEXP; ++e)
            combine[(size_t)t * NEXP + e] = (e == i1 || e == i2) ? p[e] : 0.f;
        int pos1 = atomicAdd(&count[i1], 1); rowlist[i1 * T_TOK + pos1] = t;
        int pos2 = atomicAdd(&count[i2], 1); rowlist[i2 * T_TOK + pos2] = t;
    }
}

__global__ __launch_bounds__(256, 2)
void gemm1_fb(const unsigned short* __restrict__ x_bf,
              const float* __restrict__ w1, const float* __restrict__ w3,
              unsigned short* __restrict__ h_bf,
              const int* __restrict__ rowlist, const int* __restrict__ count, int e) {
    __shared__ unsigned short aT[128 * 64];
    __shared__ unsigned short b1T[128 * 64];
    __shared__ unsigned short b3T[128 * 64];
    __shared__ int rl[128];
    const int cnt = count[e];
    const int r0 = blockIdx.y * 128;
    if (r0 >= cnt) return;
    const int n0 = blockIdx.x * 128;
    const float* __restrict__ w1e = w1 + (size_t)e * I_DIM * H_DIM;
    const float* __restrict__ w3e = w3 + (size_t)e * I_DIM * H_DIM;
    const int tid = threadIdx.x;
    if (tid < 128) {
        int r = r0 + tid;
        rl[tid] = rowlist[e * T_TOK + (r < cnt ? r : 0)];
    }
    __syncthreads();
    const int wave = tid >> 6, lane = tid & 63;
    const int wm = wave >> 1, wn = wave & 1;
    f32x4 acc1[4][4] = {};
    f32x4 acc3[4][4] = {};

    for (int kt = 0; kt < H_DIM / 64; ++kt) {
        const int k0 = kt * 64;
#pragma unroll
        for (int it = 0; it < 4; ++it) {
            int c = it * 256 + tid, row = c >> 3, slot = c & 7;
            uint4 v = *(const uint4*)(x_bf + (size_t)rl[row] * H_DIM + k0 + slot * 8);
            *(uint4*)&aT[row * 64 + ((slot ^ (row & 7)) << 3)] = v;
        }
#pragma unroll
        for (int it = 0; it < 8; ++it) {
            int c = it * 256 + tid, row = c >> 4, cw = c & 15;
            size_t goff = (size_t)(n0 + row) * H_DIM + k0 + cw * 4;
            float4 v1 = *(const float4*)(w1e + goff);
            float4 v3 = *(const float4*)(w3e + goff);
            int offr = row * 64 + (((cw >> 1) ^ (row & 7)) << 3) + (cw & 1) * 4;
            ushort4 p1 = { f2bf(v1.x), f2bf(v1.y), f2bf(v1.z), f2bf(v1.w) };
            ushort4 p3 = { f2bf(v3.x), f2bf(v3.y), f2bf(v3.z), f2bf(v3.w) };
            *(ushort4*)&b1T[offr] = p1;
            *(ushort4*)&b3T[offr] = p3;
        }
        __syncthreads();
#pragma unroll
        for (int ks = 0; ks < 2; ++ks) {
            const int slot = ks * 4 + (lane >> 4);
            bf16x8 af[4], b1f[4], b3f[4];
#pragma unroll
            for (int m = 0; m < 4; ++m) {
                int row = wm * 64 + m * 16 + (lane & 15);
                af[m] = *(const bf16x8*)&aT[row * 64 + ((slot ^ (row & 7)) << 3)];
            }
#pragma unroll
            for (int n = 0; n < 4; ++n) {
                int row = wn * 64 + n * 16 + (lane & 15);
                int offr = row * 64 + ((slot ^ (row & 7)) << 3);
                b1f[n] = *(const bf16x8*)&b1T[offr];
                b3f[n] = *(const bf16x8*)&b3T[offr];
            }
#pragma unroll
            for (int m = 0; m < 4; ++m)
#pragma unroll
                for (int n = 0; n < 4; ++n) {
                    acc1[m][n] = __builtin_amdgcn_mfma_f32_16x16x32_bf16(af[m], b1f[n], acc1[m][n], 0, 0, 0);
                    acc3[m][n] = __builtin_amdgcn_mfma_f32_16x16x32_bf16(af[m], b3f[n], acc3[m][n], 0, 0, 0);
                }
        }
        __syncthreads();
    }
#pragma unroll
    for (int m = 0; m < 4; ++m)
#pragma unroll
        for (int r = 0; r < 4; ++r) {
            int rowl = wm * 64 + m * 16 + (lane >> 4) * 4 + r;
            int ridx = r0 + rowl;
            if (ridx < cnt) {
#pragma unroll
                for (int n = 0; n < 4; ++n) {
                    int col = n0 + wn * 64 + n * 16 + (lane & 15);
                    float v1 = acc1[m][n][r], v3 = acc3[m][n][r];
                    float hv = (v1 / (1.f + expf(-v1))) * v3;
                    h_bf[(size_t)ridx * I_DIM + col] = f2bf(hv);
                }
            }
        }
}

__global__ __launch_bounds__(256, 2)
void gemm2_fb(const unsigned short* __restrict__ h_bf, const float* __restrict__ w2,
              const float* __restrict__ combine, float* __restrict__ out,
              const int* __restrict__ rowlist, const int* __restrict__ count, int e) {
    __shared__ unsigned short aT[128 * 64];
    __shared__ unsigned short bT[128 * 64];
    __shared__ int rl[128];
    const int cnt = count[e];
    const int r0 = blockIdx.y * 128;
    if (r0 >= cnt) return;
    const int n0 = blockIdx.x * 128;
    const float* __restrict__ w2e = w2 + (size_t)e * H_DIM * I_DIM;
    const int tid = threadIdx.x;
    if (tid < 128) {
        int r = r0 + tid;
        rl[tid] = rowlist[e * T_TOK + (r < cnt ? r : 0)];
    }
    __syncthreads();
    const int wave = tid >> 6, lane = tid & 63;
    const int wm = wave >> 1, wn = wave & 1;
    f32x4 acc[4][4] = {};

    for (int kt = 0; kt < I_DIM / 64; ++kt) {
        const int k0 = kt * 64;
#pragma unroll
        for (int it = 0; it < 4; ++it) {
            int c = it * 256 + tid, row = c >> 3, slot = c & 7;
            uint4 v = *(const uint4*)(h_bf + (size_t)(r0 + row) * I_DIM + k0 + slot * 8);
            *(uint4*)&aT[row * 64 + ((slot ^ (row & 7)) << 3)] = v;
        }
#pragma unroll
        for (int it = 0; it < 8; ++it) {
            int c = it * 256 + tid, row = c >> 4, cw = c & 15;
            float4 v = *(const float4*)(w2e + (size_t)(n0 + row) * I_DIM + k0 + cw * 4);
            int offr = row * 64 + (((cw >> 1) ^ (row & 7)) << 3) + (cw & 1) * 4;
            ushort4 p = { f2bf(v.x), f2bf(v.y), f2bf(v.z), f2bf(v.w) };
            *(ushort4*)&bT[offr] = p;
        }
        __syncthreads();
#pragma unroll
        for (int ks = 0; ks < 2; ++ks) {
            const int slot = ks * 4 + (lane >> 4);
            bf16x8 af[4], bfr[4];
#pragma unroll
            for (int m = 0; m < 4; ++m) {
                int row = wm * 64 + m * 16 + (lane & 15);
                af[m] = *(const bf16x8*)&aT[row * 64 + ((slot ^ (row & 7)) << 3)];
            }
#pragma unroll
            for (int n = 0; n < 4; ++n) {
                int row = wn * 64 + n * 16 + (lane & 15);
                bfr[n] = *(const bf16x8*)&bT[row * 64 + ((slot ^ (row & 7)) << 3)];
            }
#pragma unroll
            for (int m = 0; m < 4; ++m)
#pragma unroll
                for (int n = 0; n < 4; ++n)
                    acc[m][n] = __builtin_amdgcn_mfma_f32_16x16x32_bf16(af[m], bfr[n], acc[m][n], 0, 0, 0);
        }
        __syncthreads();
    }
#pragma unroll
    for (int m = 0; m < 4; ++m)
#pragma unroll
        for (int r = 0; r < 4; ++r) {
            int rowl = wm * 64 + m * 16 + (lane >> 4) * 4 + r;
            int ridx = r0 + rowl;
            if (ridx < cnt) {
                int t = rl[rowl];
                float cmb = combine[(size_t)t * NEXP + e];
#pragma unroll
                for (int n = 0; n < 4; ++n) {
                    int col = n0 + wn * 64 + n * 16 + (lane & 15);
                    out[(size_t)t * H_DIM + col] += cmb * acc[m][n][r];
                }
            }
        }
}

// ================= launch =================

extern "C" void kernel_launch(void* const* d_in, const int* in_sizes, int n_in,
                              void* d_out, int out_size, void* d_ws, size_t ws_size,
                              hipStream_t stream) {
    const float* x  = (const float*)d_in[0];
    const float* gw = (const float*)d_in[1];
    const float* gb = (const float*)d_in[2];
    const float* w1 = (const float*)d_in[3];
    const float* w2 = (const float*)d_in[4];
    const float* w3 = (const float*)d_in[5];
    float* out = (float*)d_out;
    char* ws = (char*)d_ws;

    const size_t WELEMS = (size_t)NEXP * I_DIM * H_DIM;      // 29,360,128
    // fast-path layout
    size_t off = 0;
    unsigned short* xb   = (unsigned short*)(ws + off); off += (size_t)T_TOK * H_DIM * 2;        // 16 MB
    unsigned short* w13b = (unsigned short*)(ws + off); off += WELEMS * 2 * 2;                   // 117 MB
    unsigned short* w2b  = (unsigned short*)(ws + off); off += WELEMS * 2;                       // 56 MB
    unsigned short* hb   = (unsigned short*)(ws + off); off += (size_t)MAX_TILES * 128 * I_DIM * 2; // 119 MB
    float* combine       = (float*)(ws + off);          off += (size_t)T_TOK * NEXP * 4;
    int* pair            = (int*)(ws + off);            off += (size_t)T_TOK * 4;
    int* frows           = (int*)(ws + off);            off += (size_t)MAX_TILES * 128 * 4;
    int* tile_e          = (int*)(ws + off);            off += 1024;
    int* tile_valid      = (int*)(ws + off);            off += 1024;
    int* ntiles          = (int*)(ws + off);            off += 1024;
    const size_t WS_NEEDED = off;

    (void)hipMemsetAsync(out, 0, (size_t)T_TOK * H_DIM * sizeof(float), stream);

    if (ws_size >= WS_NEEDED) {
        wcvt13_kernel<<<dim3(2048), dim3(256), 0, stream>>>(w1, w3, w13b, (int)(WELEMS * 2 / 8));
        wcvt_kernel<<<dim3(2048), dim3(256), 0, stream>>>(w2, w2b, (int)(WELEMS / 8));
        router_kernel<<<dim3(T_TOK / 4), dim3(256), 0, stream>>>(x, gw, gb, xb, combine, pair);
        build_lists_kernel<<<dim3(NEXP), dim3(1024), 0, stream>>>(pair, frows, tile_e, tile_valid, ntiles);
        gemm1_kernel<<<dim3(7168 / 128, MAX_TILES), dim3(256), 0, stream>>>(
            xb, w13b, hb, frows, tile_e, ntiles);
        gemm2_kernel<<<dim3(H_DIM / 128, MAX_TILES), dim3(256), 0, stream>>>(
            hb, w2b, combine, out, frows, tile_e, tile_valid, ntiles);
    } else {
        // fallback: R1 layout (76 MB)
        unsigned short* x_bf    = (unsigned short*)ws;
        unsigned short* h_bf    = (unsigned short*)(ws + 16777216);
        float*          fcomb   = (float*)(ws + 16777216 + 58720256);
        int*            rowlist = (int*)(ws + 16777216 + 58720256 + 262144);
        int*            count   = (int*)(ws + 16777216 + 58720256 + 262144 + 262144);

        (void)hipMemsetAsync(count, 0, NEXP * sizeof(int), stream);
        cvt_x_fb<<<dim3(T_TOK * H_DIM / (256 * 8)), dim3(256), 0, stream>>>(x, x_bf);
        router_fb<<<dim3(T_TOK / 4), dim3(256), 0, stream>>>(x, gw, gb, fcomb, rowlist, count);
        for (int e = 0; e < NEXP; ++e) {
            gemm1_fb<<<dim3(I_DIM / 128, T_TOK / 128), dim3(256), 0, stream>>>(
                x_bf, w1, w3, h_bf, rowlist, count, e);
            gemm2_fb<<<dim3(H_DIM / 128, T_TOK / 128), dim3(256), 0, stream>>>(
                h_bf, w2, fcomb, out, rowlist, count, e);
        }
    }
}

// Round 13
// 593.985 us; speedup vs baseline: 1.0790x; 1.0028x over previous
//
#include <hip/hip_runtime.h>

#define T_TOK 8192
#define H_DIM 1024
#define I_DIM 3584
#define NEXP 8
#define MAX_TILES 136          // sum ceil(cnt_e/128) <= 128 + 7, padded

typedef __attribute__((ext_vector_type(4))) float f32x4;
typedef __attribute__((ext_vector_type(8))) short bf16x8;

__device__ __forceinline__ unsigned short f2bf(float f) {
    union { float f; unsigned u; } v; v.f = f;
    unsigned r = v.u + 0x7FFFu + ((v.u >> 16) & 1u);
    return (unsigned short)(r >> 16);
}

__device__ __forceinline__ void gload16(const unsigned short* g, unsigned short* l) {
    __builtin_amdgcn_global_load_lds(
        (const __attribute__((address_space(1))) void*)g,
        (__attribute__((address_space(3))) void*)l, 16, 0, 0);
}

// ================= fast path =================

// router: logits -> softmax -> top2; emits pair[t], combine[t][8], and xb (bf16 x)
__global__ void router_kernel(const float* __restrict__ x, const float* __restrict__ gw,
                              const float* __restrict__ gb, unsigned short* __restrict__ xb,
                              float* __restrict__ combine, int* __restrict__ pair) {
    int wave = threadIdx.x >> 6, lane = threadIdx.x & 63;
    int t = blockIdx.x * 4 + wave;
    float acc[NEXP];
#pragma unroll
    for (int e = 0; e < NEXP; ++e) acc[e] = 0.f;
    const float4* xr = (const float4*)(x + (size_t)t * H_DIM);
#pragma unroll
    for (int j = 0; j < 4; ++j) {
        int c = j * 64 + lane;
        float4 xv = xr[c];
        ushort4 o = { f2bf(xv.x), f2bf(xv.y), f2bf(xv.z), f2bf(xv.w) };
        *(ushort4*)(xb + (size_t)t * H_DIM + c * 4) = o;
#pragma unroll
        for (int e = 0; e < NEXP; ++e) {
            float4 gv = ((const float4*)(gw + (size_t)e * H_DIM))[c];
            acc[e] += xv.x * gv.x + xv.y * gv.y + xv.z * gv.z + xv.w * gv.w;
        }
    }
#pragma unroll
    for (int off = 32; off; off >>= 1)
#pragma unroll
        for (int e = 0; e < NEXP; ++e) acc[e] += __shfl_xor(acc[e], off, 64);
    if (lane == 0) {
        float logit[NEXP], mx = -1e30f;
#pragma unroll
        for (int e = 0; e < NEXP; ++e) { logit[e] = acc[e] + gb[e]; mx = fmaxf(mx, logit[e]); }
        float p[NEXP], s = 0.f;
#pragma unroll
        for (int e = 0; e < NEXP; ++e) { p[e] = expf(logit[e] - mx); s += p[e]; }
        float inv = 1.f / s;
#pragma unroll
        for (int e = 0; e < NEXP; ++e) p[e] *= inv;
        int i1 = 0;
#pragma unroll
        for (int e = 1; e < NEXP; ++e) if (p[e] > p[i1]) i1 = e;
        int i2 = -1;
#pragma unroll
        for (int e = 0; e < NEXP; ++e) if (e != i1 && (i2 < 0 || p[e] > p[i2])) i2 = e;
        float4 c0, c1;
        c0.x = (0 == i1 || 0 == i2) ? p[0] : 0.f;  c0.y = (1 == i1 || 1 == i2) ? p[1] : 0.f;
        c0.z = (2 == i1 || 2 == i2) ? p[2] : 0.f;  c0.w = (3 == i1 || 3 == i2) ? p[3] : 0.f;
        c1.x = (4 == i1 || 4 == i2) ? p[4] : 0.f;  c1.y = (5 == i1 || 5 == i2) ? p[5] : 0.f;
        c1.z = (6 == i1 || 6 == i2) ? p[6] : 0.f;  c1.w = (7 == i1 || 7 == i2) ? p[7] : 0.f;
        *(float4*)(combine + (size_t)t * NEXP) = c0;
        *(float4*)(combine + (size_t)t * NEXP + 4) = c1;
        pair[t] = i1 | (i2 << 8);
    }
}

// deterministic, atomic-free list builder: 8 blocks (one per expert), 1024 threads.
__global__ void build_lists_kernel(const int* __restrict__ pair, int* __restrict__ frows,
                                   int* __restrict__ tile_e, int* __restrict__ tile_valid,
                                   int* __restrict__ ntiles) {
    const int e = blockIdx.x;
    const int tid = threadIdx.x;
    const int wave = tid >> 6, lane = tid & 63;
    __shared__ int wtot[16][NEXP];
    __shared__ int stot[NEXP];
    __shared__ int wcnt[16];

    int myp[8];
    int tcnt[NEXP] = {0, 0, 0, 0, 0, 0, 0, 0};
#pragma unroll
    for (int c = 0; c < 8; ++c) {
        int pr = pair[c * 1024 + tid];
        myp[c] = pr;
        int e1 = pr & 255, e2 = (pr >> 8) & 255;
#pragma unroll
        for (int j = 0; j < NEXP; ++j) {
            unsigned long long m = __ballot(e1 == j || e2 == j);
            if (lane == 0) tcnt[j] += (int)__popcll(m);
        }
    }
    if (lane == 0) {
#pragma unroll
        for (int j = 0; j < NEXP; ++j) wtot[wave][j] = tcnt[j];
    }
    __syncthreads();
    if (tid < NEXP) {
        int s = 0;
        for (int w = 0; w < 16; ++w) s += wtot[w][tid];
        stot[tid] = s;
    }
    __syncthreads();

    int gbase = 0, tbase = 0, totTiles = 0;
#pragma unroll
    for (int j = 0; j < NEXP; ++j) {
        int tj = (stot[j] + 127) >> 7;
        if (j < e) { gbase += tj << 7; tbase += tj; }
        totTiles += tj;
    }
    const int cnt = stot[e];
    const int mytiles = (cnt + 127) >> 7;

    int base = gbase;
    for (int c = 0; c < 8; ++c) {
        int pr = myp[c];
        bool pred = ((pr & 255) == e) || (((pr >> 8) & 255) == e);
        unsigned long long m = __ballot(pred);
        if (lane == 0) wcnt[wave] = (int)__popcll(m);
        __syncthreads();
        int wb = 0;
        for (int w = 0; w < wave; ++w) wb += wcnt[w];
        int ctot = 0;
        for (int w = 0; w < 16; ++w) ctot += wcnt[w];
        if (pred) {
            int wp = (int)__popcll(m & ((1ull << lane) - 1ull));
            frows[base + wb + wp] = c * 1024 + tid;
        }
        base += ctot;
        __syncthreads();
    }
    if (cnt > 0) {
        int first = frows[gbase];
        for (int p = cnt + tid; p < (mytiles << 7); p += 1024) frows[gbase + p] = first;
        if (tid < mytiles) {
            tile_e[tbase + tid] = e;
            int v = cnt - (tid << 7);
            tile_valid[tbase + tid] = v > 128 ? 128 : v;
        }
    }
    if (e == 0 && tid == 0) ntiles[0] = totTiles;
}

// weights f32 -> bf16 (grid-stride, 8 elems/thread)
__global__ void wcvt_kernel(const float* __restrict__ src, unsigned short* __restrict__ dst, int n8) {
    int stride = gridDim.x * blockDim.x;
    for (int i = blockIdx.x * blockDim.x + threadIdx.x; i < n8; i += stride) {
        const float4* p = (const float4*)src + (size_t)i * 2;
        float4 a = p[0], b = p[1];
        uint4 o;
        o.x = (unsigned)f2bf(a.x) | ((unsigned)f2bf(a.y) << 16);
        o.y = (unsigned)f2bf(a.z) | ((unsigned)f2bf(a.w) << 16);
        o.z = (unsigned)f2bf(b.x) | ((unsigned)f2bf(b.y) << 16);
        o.w = (unsigned)f2bf(b.z) | ((unsigned)f2bf(b.w) << 16);
        *(uint4*)(dst + (size_t)i * 8) = o;
    }
}

// w1,w3 f32 -> interleaved bf16 w13i[e][7168][1024] (R7/R8/R12-verified):
// row r: s=r&31, rg=r>>5; s<16 -> w1 row rg*16+s ; s>=16 -> w3 row rg*16+s-16
__global__ void wcvt13_kernel(const float* __restrict__ w1, const float* __restrict__ w3,
                              unsigned short* __restrict__ dst, int n8) {
    int stride = gridDim.x * blockDim.x;
    for (int g = blockIdx.x * blockDim.x + threadIdx.x; g < n8; g += stride) {
        int col = (g & 127) * 8;
        int er = g >> 7;
        int r = er % 7168;
        int e = er / 7168;
        int s = r & 31, rg = r >> 5;
        const float* src = (s < 16)
            ? (w1 + ((size_t)e * I_DIM + rg * 16 + s) * H_DIM + col)
            : (w3 + ((size_t)e * I_DIM + rg * 16 + (s - 16)) * H_DIM + col);
        float4 a = *(const float4*)src;
        float4 b = *(const float4*)(src + 4);
        uint4 o;
        o.x = (unsigned)f2bf(a.x) | ((unsigned)f2bf(a.y) << 16);
        o.y = (unsigned)f2bf(a.z) | ((unsigned)f2bf(a.w) << 16);
        o.z = (unsigned)f2bf(b.x) | ((unsigned)f2bf(b.y) << 16);
        o.w = (unsigned)f2bf(b.z) | ((unsigned)f2bf(b.w) << 16);
        *(uint4*)(dst + (size_t)g * 8) = o;
    }
}

// GEMM1 (single-B via interleaved w13i, R12-verified): h = silu(Xg*W1e^T) * (Xg*W3e^T)
// 128x128 tile, LDS 32KB, 64 AGPR + ~72 VGPR -> (256,3): 3 blocks/CU, 12 waves/CU.
__global__ __launch_bounds__(256, 3)
void gemm1_kernel(const unsigned short* __restrict__ xb,
                  const unsigned short* __restrict__ w13b,
                  unsigned short* __restrict__ h_bf,
                  const int* __restrict__ frows, const int* __restrict__ tile_e,
                  const int* __restrict__ ntiles) {
    const int bt = blockIdx.y;
    if (bt >= ntiles[0]) return;
    __shared__ unsigned short aT[128 * 64];
    __shared__ unsigned short bT[128 * 64];
    const int e = tile_e[bt];
    const int n0w = blockIdx.x * 128;          // interleaved-row base
    const int tid = threadIdx.x, wave = tid >> 6, lane = tid & 63;
    const int wm = wave >> 1, wn = wave & 1;

    const int sslot = (lane & 7) ^ (lane >> 3);
    const unsigned short *aS[4], *bS[4];
    unsigned short *aD[4], *bD[4];
#pragma unroll
    for (int i = 0; i < 4; ++i) {
        int rowl = wave * 32 + i * 8 + (lane >> 3);
        int tok = frows[bt * 128 + rowl];
        int c8 = sslot * 8;
        aS[i] = xb   + (size_t)tok * H_DIM + c8;
        bS[i] = w13b + ((size_t)e * 7168 + n0w + rowl) * H_DIM + c8;
        int r0l = wave * 32 + i * 8;
        aD[i] = &aT[r0l * 64]; bD[i] = &bT[r0l * 64];
    }
    f32x4 acc[4][4] = {};

    for (int kt = 0; kt < H_DIM / 64; ++kt) {
#pragma unroll
        for (int i = 0; i < 4; ++i) {
            gload16(aS[i], aD[i]);
            gload16(bS[i], bD[i]);
            aS[i] += 64; bS[i] += 64;
        }
        __syncthreads();
#pragma unroll
        for (int ks = 0; ks < 2; ++ks) {
            const int slot = ks * 4 + (lane >> 4);
            bf16x8 af[4], bfr[4];
#pragma unroll
            for (int m = 0; m < 4; ++m) {
                int row = wm * 64 + m * 16 + (lane & 15);
                af[m] = *(const bf16x8*)&aT[row * 64 + ((slot ^ (row & 7)) << 3)];
            }
#pragma unroll
            for (int n = 0; n < 4; ++n) {
                int row = wn * 64 + n * 16 + (lane & 15);
                bfr[n] = *(const bf16x8*)&bT[row * 64 + ((slot ^ (row & 7)) << 3)];
            }
#pragma unroll
            for (int m = 0; m < 4; ++m)
#pragma unroll
                for (int n = 0; n < 4; ++n)
                    acc[m][n] = __builtin_amdgcn_mfma_f32_16x16x32_bf16(af[m], bfr[n], acc[m][n], 0, 0, 0);
        }
        __syncthreads();
    }
    // epilogue: n=2u is a w1 16-row group, n=2u+1 the matching w3 group.
#pragma unroll
    for (int m = 0; m < 4; ++m)
#pragma unroll
        for (int r = 0; r < 4; ++r) {
            int rowl = wm * 64 + m * 16 + (lane >> 4) * 4 + r;
            size_t hoff = (size_t)(bt * 128 + rowl) * I_DIM;
#pragma unroll
            for (int u = 0; u < 2; ++u) {
                int icol = blockIdx.x * 64 + wn * 32 + u * 16 + (lane & 15);
                float v1 = acc[m][2 * u][r], v3 = acc[m][2 * u + 1][r];
                float hv = (v1 / (1.f + expf(-v1))) * v3;
                h_bf[hoff + icol] = f2bf(hv);
            }
        }
}

// GEMM2 (flat): out[t,:] += combine[t,e] * (Hg * W2e^T)
// Same footprint as gemm1 (32KB LDS, 64 AGPR, ~72 VGPR) -> (256,3) for 3 blocks/CU
// (R12 proved this footprint fits; R5's spill was the 128-AGPR dual-acc kernel).
// atomicAdd writeback: exactly 2 contributions per element onto zeroed out; deterministic.
__global__ __launch_bounds__(256, 3)
void gemm2_kernel(const unsigned short* __restrict__ h_bf, const unsigned short* __restrict__ w2b,
                  const float* __restrict__ combine, float* __restrict__ out,
                  const int* __restrict__ frows, const int* __restrict__ tile_e,
                  const int* __restrict__ tile_valid, const int* __restrict__ ntiles) {
    const int bt = blockIdx.y;
    if (bt >= ntiles[0]) return;
    __shared__ unsigned short aT[128 * 64];
    __shared__ unsigned short bT[128 * 64];
    const int e = tile_e[bt];
    const int valid = tile_valid[bt];
    const int n0 = blockIdx.x * 128;
    const int tid = threadIdx.x, wave = tid >> 6, lane = tid & 63;
    const int wm = wave >> 1, wn = wave & 1;

    const int sslot = (lane & 7) ^ (lane >> 3);
    const unsigned short *aS[4], *bS[4];
    unsigned short *aD[4], *bD[4];
#pragma unroll
    for (int i = 0; i < 4; ++i) {
        int rowl = wave * 32 + i * 8 + (lane >> 3);
        int c8 = sslot * 8;
        aS[i] = h_bf + (size_t)(bt * 128 + rowl) * I_DIM + c8;
        bS[i] = w2b + ((size_t)e * H_DIM + n0 + rowl) * I_DIM + c8;
        int r0l = wave * 32 + i * 8;
        aD[i] = &aT[r0l * 64]; bD[i] = &bT[r0l * 64];
    }
    f32x4 acc[4][4] = {};

    for (int kt = 0; kt < I_DIM / 64; ++kt) {
#pragma unroll
        for (int i = 0; i < 4; ++i) {
            gload16(aS[i], aD[i]);
            gload16(bS[i], bD[i]);
            aS[i] += 64; bS[i] += 64;
        }
        __syncthreads();
#pragma unroll
        for (int ks = 0; ks < 2; ++ks) {
            const int slot = ks * 4 + (lane >> 4);
            bf16x8 af[4], bfr[4];
#pragma unroll
            for (int m = 0; m < 4; ++m) {
                int row = wm * 64 + m * 16 + (lane & 15);
                af[m] = *(const bf16x8*)&aT[row * 64 + ((slot ^ (row & 7)) << 3)];
            }
#pragma unroll
            for (int n = 0; n < 4; ++n) {
                int row = wn * 64 + n * 16 + (lane & 15);
                bfr[n] = *(const bf16x8*)&bT[row * 64 + ((slot ^ (row & 7)) << 3)];
            }
#pragma unroll
            for (int m = 0; m < 4; ++m)
#pragma unroll
                for (int n = 0; n < 4; ++n)
                    acc[m][n] = __builtin_amdgcn_mfma_f32_16x16x32_bf16(af[m], bfr[n], acc[m][n], 0, 0, 0);
        }
        __syncthreads();
    }
#pragma unroll
    for (int m = 0; m < 4; ++m)
#pragma unroll
        for (int r = 0; r < 4; ++r) {
            int rowl = wm * 64 + m * 16 + (lane >> 4) * 4 + r;
            if (rowl < valid) {
                int t = frows[bt * 128 + rowl];
                float cmb = combine[(size_t)t * NEXP + e];
#pragma unroll
                for (int n = 0; n < 4; ++n) {
                    int col = n0 + wn * 64 + n * 16 + (lane & 15);
                    atomicAdd(&out[(size_t)t * H_DIM + col], cmb * acc[m][n][r]);
                }
            }
        }
}

// ================= fallback path (R1, verified) =================

__global__ void cvt_x_fb(const float* __restrict__ x, unsigned short* __restrict__ xb) {
    size_t i = (size_t)blockIdx.x * blockDim.x + threadIdx.x;
    const float4* p = (const float4*)x + i * 2;
    float4 a = p[0], b = p[1];
    uint4 o;
    o.x = (unsigned)f2bf(a.x) | ((unsigned)f2bf(a.y) << 16);
    o.y = (unsigned)f2bf(a.z) | ((unsigned)f2bf(a.w) << 16);
    o.z = (unsigned)f2bf(b.x) | ((unsigned)f2bf(b.y) << 16);
    o.w = (unsigned)f2bf(b.z) | ((unsigned)f2bf(b.w) << 16);
    *(uint4*)(xb + i * 8) = o;
}

__global__ void router_fb(const float* __restrict__ x, const float* __restrict__ gw,
                          const float* __restrict__ gb, float* __restrict__ combine,
                          int* __restrict__ rowlist, int* __restrict__ count) {
    int wave = threadIdx.x >> 6, lane = threadIdx.x & 63;
    int t = blockIdx.x * 4 + wave;
    float acc[NEXP];
#pragma unroll
    for (int e = 0; e < NEXP; ++e) acc[e] = 0.f;
    const float4* xr = (const float4*)(x + (size_t)t * H_DIM);
#pragma unroll
    for (int j = 0; j < 4; ++j) {
        int c = j * 64 + lane;
        float4 xv = xr[c];
#pragma unroll
        for (int e = 0; e < NEXP; ++e) {
            float4 gv = ((const float4*)(gw + (size_t)e * H_DIM))[c];
            acc[e] += xv.x * gv.x + xv.y * gv.y + xv.z * gv.z + xv.w * gv.w;
        }
    }
#pragma unroll
    for (int off = 32; off; off >>= 1)
#pragma unroll
        for (int e = 0; e < NEXP; ++e) acc[e] += __shfl_xor(acc[e], off, 64);
    if (lane == 0) {
        float logit[NEXP], mx = -1e30f;
#pragma unroll
        for (int e = 0; e < NEXP; ++e) { logit[e] = acc[e] + gb[e]; mx = fmaxf(mx, logit[e]); }
        float p[NEXP], s = 0.f;
#pragma unroll
        for (int e = 0; e < NEXP; ++e) { p[e] = expf(logit[e] - mx); s += p[e]; }
        float inv = 1.f / s;
#pragma unroll
        for (int e = 0; e < NEXP; ++e) p[e] *= inv;
        int i1 = 0;
#pragma unroll
        for (int e = 1; e < NEXP; ++e) if (p[e] > p[i1]) i1 = e;
        int i2 = -1;
#pragma unroll
        for (int e = 0; e < NEXP; ++e) if (e != i1 && (i2 < 0 || p[e] > p[i2])) i2 = e;
#pragma unroll
        for (int e = 0; e < NEXP; ++e)
            combine[(size_t)t * NEXP + e] = (e == i1 || e == i2) ? p[e] : 0.f;
        int pos1 = atomicAdd(&count[i1], 1); rowlist[i1 * T_TOK + pos1] = t;
        int pos2 = atomicAdd(&count[i2], 1); rowlist[i2 * T_TOK + pos2] = t;
    }
}

__global__ __launch_bounds__(256, 2)
void gemm1_fb(const unsigned short* __restrict__ x_bf,
              const float* __restrict__ w1, const float* __restrict__ w3,
              unsigned short* __restrict__ h_bf,
              const int* __restrict__ rowlist, const int* __restrict__ count, int e) {
    __shared__ unsigned short aT[128 * 64];
    __shared__ unsigned short b1T[128 * 64];
    __shared__ unsigned short b3T[128 * 64];
    __shared__ int rl[128];
    const int cnt = count[e];
    const int r0 = blockIdx.y * 128;
    if (r0 >= cnt) return;
    const int n0 = blockIdx.x * 128;
    const float* __restrict__ w1e = w1 + (size_t)e * I_DIM * H_DIM;
    const float* __restrict__ w3e = w3 + (size_t)e * I_DIM * H_DIM;
    const int tid = threadIdx.x;
    if (tid < 128) {
        int r = r0 + tid;
        rl[tid] = rowlist[e * T_TOK + (r < cnt ? r : 0)];
    }
    __syncthreads();
    const int wave = tid >> 6, lane = tid & 63;
    const int wm = wave >> 1, wn = wave & 1;
    f32x4 acc1[4][4] = {};
    f32x4 acc3[4][4] = {};

    for (int kt = 0; kt < H_DIM / 64; ++kt) {
        const int k0 = kt * 64;
#pragma unroll
        for (int it = 0; it < 4; ++it) {
            int c = it * 256 + tid, row = c >> 3, slot = c & 7;
            uint4 v = *(const uint4*)(x_bf + (size_t)rl[row] * H_DIM + k0 + slot * 8);
            *(uint4*)&aT[row * 64 + ((slot ^ (row & 7)) << 3)] = v;
        }
#pragma unroll
        for (int it = 0; it < 8; ++it) {
            int c = it * 256 + tid, row = c >> 4, cw = c & 15;
            size_t goff = (size_t)(n0 + row) * H_DIM + k0 + cw * 4;
            float4 v1 = *(const float4*)(w1e + goff);
            float4 v3 = *(const float4*)(w3e + goff);
            int offr = row * 64 + (((cw >> 1) ^ (row & 7)) << 3) + (cw & 1) * 4;
            ushort4 p1 = { f2bf(v1.x), f2bf(v1.y), f2bf(v1.z), f2bf(v1.w) };
            ushort4 p3 = { f2bf(v3.x), f2bf(v3.y), f2bf(v3.z), f2bf(v3.w) };
            *(ushort4*)&b1T[offr] = p1;
            *(ushort4*)&b3T[offr] = p3;
        }
        __syncthreads();
#pragma unroll
        for (int ks = 0; ks < 2; ++ks) {
            const int slot = ks * 4 + (lane >> 4);
            bf16x8 af[4], b1f[4], b3f[4];
#pragma unroll
            for (int m = 0; m < 4; ++m) {
                int row = wm * 64 + m * 16 + (lane & 15);
                af[m] = *(const bf16x8*)&aT[row * 64 + ((slot ^ (row & 7)) << 3)];
            }
#pragma unroll
            for (int n = 0; n < 4; ++n) {
                int row = wn * 64 + n * 16 + (lane & 15);
                int offr = row * 64 + ((slot ^ (row & 7)) << 3);
                b1f[n] = *(const bf16x8*)&b1T[offr];
                b3f[n] = *(const bf16x8*)&b3T[offr];
            }
#pragma unroll
            for (int m = 0; m < 4; ++m)
#pragma unroll
                for (int n = 0; n < 4; ++n) {
                    acc1[m][n] = __builtin_amdgcn_mfma_f32_16x16x32_bf16(af[m], b1f[n], acc1[m][n], 0, 0, 0);
                    acc3[m][n] = __builtin_amdgcn_mfma_f32_16x16x32_bf16(af[m], b3f[n], acc3[m][n], 0, 0, 0);
                }
        }
        __syncthreads();
    }
#pragma unroll
    for (int m = 0; m < 4; ++m)
#pragma unroll
        for (int r = 0; r < 4; ++r) {
            int rowl = wm * 64 + m * 16 + (lane >> 4) * 4 + r;
            int ridx = r0 + rowl;
            if (ridx < cnt) {
#pragma unroll
                for (int n = 0; n < 4; ++n) {
                    int col = n0 + wn * 64 + n * 16 + (lane & 15);
                    float v1 = acc1[m][n][r], v3 = acc3[m][n][r];
                    float hv = (v1 / (1.f + expf(-v1))) * v3;
                    h_bf[(size_t)ridx * I_DIM + col] = f2bf(hv);
                }
            }
        }
}

__global__ __launch_bounds__(256, 2)
void gemm2_fb(const unsigned short* __restrict__ h_bf, const float* __restrict__ w2,
              const float* __restrict__ combine, float* __restrict__ out,
              const int* __restrict__ rowlist, const int* __restrict__ count, int e) {
    __shared__ unsigned short aT[128 * 64];
    __shared__ unsigned short bT[128 * 64];
    __shared__ int rl[128];
    const int cnt = count[e];
    const int r0 = blockIdx.y * 128;
    if (r0 >= cnt) return;
    const int n0 = blockIdx.x * 128;
    const float* __restrict__ w2e = w2 + (size_t)e * H_DIM * I_DIM;
    const int tid = threadIdx.x;
    if (tid < 128) {
        int r = r0 + tid;
        rl[tid] = rowlist[e * T_TOK + (r < cnt ? r : 0)];
    }
    __syncthreads();
    const int wave = tid >> 6, lane = tid & 63;
    const int wm = wave >> 1, wn = wave & 1;
    f32x4 acc[4][4] = {};

    for (int kt = 0; kt < I_DIM / 64; ++kt) {
        const int k0 = kt * 64;
#pragma unroll
        for (int it = 0; it < 4; ++it) {
            int c = it * 256 + tid, row = c >> 3, slot = c & 7;
            uint4 v = *(const uint4*)(h_bf + (size_t)(r0 + row) * I_DIM + k0 + slot * 8);
            *(uint4*)&aT[row * 64 + ((slot ^ (row & 7)) << 3)] = v;
        }
#pragma unroll
        for (int it = 0; it < 8; ++it) {
            int c = it * 256 + tid, row = c >> 4, cw = c & 15;
            float4 v = *(const float4*)(w2e + (size_t)(n0 + row) * I_DIM + k0 + cw * 4);
            int offr = row * 64 + (((cw >> 1) ^ (row & 7)) << 3) + (cw & 1) * 4;
            ushort4 p = { f2bf(v.x), f2bf(v.y), f2bf(v.z), f2bf(v.w) };
            *(ushort4*)&bT[offr] = p;
        }
        __syncthreads();
#pragma unroll
        for (int ks = 0; ks < 2; ++ks) {
            const int slot = ks * 4 + (lane >> 4);
            bf16x8 af[4], bfr[4];
#pragma unroll
            for (int m = 0; m < 4; ++m) {
                int row = wm * 64 + m * 16 + (lane & 15);
                af[m] = *(const bf16x8*)&aT[row * 64 + ((slot ^ (row & 7)) << 3)];
            }
#pragma unroll
            for (int n = 0; n < 4; ++n) {
                int row = wn * 64 + n * 16 + (lane & 15);
                bfr[n] = *(const bf16x8*)&bT[row * 64 + ((slot ^ (row & 7)) << 3)];
            }
#pragma unroll
            for (int m = 0; m < 4; ++m)
#pragma unroll
                for (int n = 0; n < 4; ++n)
                    acc[m][n] = __builtin_amdgcn_mfma_f32_16x16x32_bf16(af[m], bfr[n], acc[m][n], 0, 0, 0);
        }
        __syncthreads();
    }
#pragma unroll
    for (int m = 0; m < 4; ++m)
#pragma unroll
        for (int r = 0; r < 4; ++r) {
            int rowl = wm * 64 + m * 16 + (lane >> 4) * 4 + r;
            int ridx = r0 + rowl;
            if (ridx < cnt) {
                int t = rl[rowl];
                float cmb = combine[(size_t)t * NEXP + e];
#pragma unroll
                for (int n = 0; n < 4; ++n) {
                    int col = n0 + wn * 64 + n * 16 + (lane & 15);
                    out[(size_t)t * H_DIM + col] += cmb * acc[m][n][r];
                }
            }
        }
}

// ================= launch =================

extern "C" void kernel_launch(void* const* d_in, const int* in_sizes, int n_in,
                              void* d_out, int out_size, void* d_ws, size_t ws_size,
                              hipStream_t stream) {
    const float* x  = (const float*)d_in[0];
    const float* gw = (const float*)d_in[1];
    const float* gb = (const float*)d_in[2];
    const float* w1 = (const float*)d_in[3];
    const float* w2 = (const float*)d_in[4];
    const float* w3 = (const float*)d_in[5];
    float* out = (float*)d_out;
    char* ws = (char*)d_ws;

    const size_t WELEMS = (size_t)NEXP * I_DIM * H_DIM;      // 29,360,128
    // fast-path layout
    size_t off = 0;
    unsigned short* xb   = (unsigned short*)(ws + off); off += (size_t)T_TOK * H_DIM * 2;        // 16 MB
    unsigned short* w13b = (unsigned short*)(ws + off); off += WELEMS * 2 * 2;                   // 117 MB
    unsigned short* w2b  = (unsigned short*)(ws + off); off += WELEMS * 2;                       // 56 MB
    unsigned short* hb   = (unsigned short*)(ws + off); off += (size_t)MAX_TILES * 128 * I_DIM * 2; // 119 MB
    float* combine       = (float*)(ws + off);          off += (size_t)T_TOK * NEXP * 4;
    int* pair            = (int*)(ws + off);            off += (size_t)T_TOK * 4;
    int* frows           = (int*)(ws + off);            off += (size_t)MAX_TILES * 128 * 4;
    int* tile_e          = (int*)(ws + off);            off += 1024;
    int* tile_valid      = (int*)(ws + off);            off += 1024;
    int* ntiles          = (int*)(ws + off);            off += 1024;
    const size_t WS_NEEDED = off;

    (void)hipMemsetAsync(out, 0, (size_t)T_TOK * H_DIM * sizeof(float), stream);

    if (ws_size >= WS_NEEDED) {
        wcvt13_kernel<<<dim3(2048), dim3(256), 0, stream>>>(w1, w3, w13b, (int)(WELEMS * 2 / 8));
        wcvt_kernel<<<dim3(2048), dim3(256), 0, stream>>>(w2, w2b, (int)(WELEMS / 8));
        router_kernel<<<dim3(T_TOK / 4), dim3(256), 0, stream>>>(x, gw, gb, xb, combine, pair);
        build_lists_kernel<<<dim3(NEXP), dim3(1024), 0, stream>>>(pair, frows, tile_e, tile_valid, ntiles);
        gemm1_kernel<<<dim3(7168 / 128, MAX_TILES), dim3(256), 0, stream>>>(
            xb, w13b, hb, frows, tile_e, ntiles);
        gemm2_kernel<<<dim3(H_DIM / 128, MAX_TILES), dim3(256), 0, stream>>>(
            hb, w2b, combine, out, frows, tile_e, tile_valid, ntiles);
    } else {
        // fallback: R1 layout (76 MB)
        unsigned short* x_bf    = (unsigned short*)ws;
        unsigned short* h_bf    = (unsigned short*)(ws + 16777216);
        float*          fcomb   = (float*)(ws + 16777216 + 58720256);
        int*            rowlist = (int*)(ws + 16777216 + 58720256 + 262144);
        int*            count   = (int*)(ws + 16777216 + 58720256 + 262144 + 262144);

        (void)hipMemsetAsync(count, 0, NEXP * sizeof(int), stream);
        cvt_x_fb<<<dim3(T_TOK * H_DIM / (256 * 8)), dim3(256), 0, stream>>>(x, x_bf);
        router_fb<<<dim3(T_TOK / 4), dim3(256), 0, stream>>>(x, gw, gb, fcomb, rowlist, count);
        for (int e = 0; e < NEXP; ++e) {
            gemm1_fb<<<dim3(I_DIM / 128, T_TOK / 128), dim3(256), 0, stream>>>(
                x_bf, w1, w3, h_bf, rowlist, count, e);
            gemm2_fb<<<dim3(H_DIM / 128, T_TOK / 128), dim3(256), 0, stream>>>(
                h_bf, w2, fcomb, out, rowlist, count, e);
        }
    }
}